// Round 3
// baseline (769.840 us; speedup 1.0000x reference)
//
#include <hip/hip_runtime.h>
#include <stdint.h>

typedef __attribute__((ext_vector_type(8))) short v8s;
typedef __attribute__((ext_vector_type(4))) float v4f;

#define DEV static __device__ __forceinline__

DEV unsigned short f2bf(float f) {
  union { float f; unsigned int u; } v; v.f = f;
  unsigned int u = v.u;
  return (unsigned short)((u + 0x7fffu + ((u >> 16) & 1u)) >> 16);
}

DEV v4f mfma16(v8s a, v8s b, v4f c) {
  return __builtin_amdgcn_mfma_f32_16x16x32_bf16(a, b, c, 0, 0, 0);
}

DEV void async16(const void* g, void* lds) {
  __builtin_amdgcn_global_load_lds((const __attribute__((address_space(1))) unsigned int*)g,
                                   (__attribute__((address_space(3))) unsigned int*)lds,
                                   16, 0, 0);
}

// ---------------- elementwise f32 -> bf16 ----------------
__global__ __launch_bounds__(256) void k_f32_to_bf16(const float* __restrict__ in,
                                                     unsigned short* __restrict__ out, int n4) {
  int i = blockIdx.x * 256 + threadIdx.x;
  if (i < n4) {
    float4 v = reinterpret_cast<const float4*>(in)[i];
    ushort4 o;
    o.x = f2bf(v.x); o.y = f2bf(v.y); o.z = f2bf(v.z); o.w = f2bf(v.w);
    reinterpret_cast<ushort4*>(out)[i] = o;
  }
}

// ---------------- transpose+convert: in [R][C] f32 -> out [C][R] bf16 ----------------
__global__ __launch_bounds__(256) void k_transpose(const float* __restrict__ in,
                                                   unsigned short* __restrict__ out, int R, int C) {
  __shared__ float tile[64][65];
  const int r0 = blockIdx.x * 64, c0 = blockIdx.y * 64;
  const int t = threadIdx.x;
  const int rl = t >> 4, cl = (t & 15) * 4;
#pragma unroll
  for (int p = 0; p < 4; p++) {
    const int r = rl + p * 16;
    float4 v = *reinterpret_cast<const float4*>(&in[(size_t)(r0 + r) * C + c0 + cl]);
    tile[r][cl] = v.x; tile[r][cl + 1] = v.y; tile[r][cl + 2] = v.z; tile[r][cl + 3] = v.w;
  }
  __syncthreads();
  const int cw = t >> 4, rw = (t & 15) * 4;
#pragma unroll
  for (int p = 0; p < 4; p++) {
    const int c = cw + p * 16;
    ushort4 o;
    o.x = f2bf(tile[rw + 0][c]); o.y = f2bf(tile[rw + 1][c]);
    o.z = f2bf(tile[rw + 2][c]); o.w = f2bf(tile[rw + 3][c]);
    *reinterpret_cast<ushort4*>(&out[(size_t)(c0 + c) * R + r0 + rw]) = o;
  }
}

// ---------------- GEMM 128x128 tile, BK=32, bf16 MFMA, f32 accum ----------------
// A[M,K] bf16 (row amap), Bt[N,K] bf16.
// MODE 0: Cout[row][N] f32 = acc + bias, row via amap.
// MODE 1: fused qkv epilogue. n-tile == one head of q/k/v.
//   q,k: bias -> rmsnorm (cross-wave LDS reduce) -> rope(upper 64 ch) -> bf16 [bh][2560][128]
//   v:   bias -> bf16 transposed [bh][128][2560]
template <int MODE>
__global__ __launch_bounds__(256) void k_gemm(
    const unsigned short* __restrict__ A, const unsigned short* __restrict__ Bt,
    const float* __restrict__ bias, float* __restrict__ Cout,
    unsigned short* __restrict__ Qb, unsigned short* __restrict__ Kb,
    unsigned short* __restrict__ Vt, const float* __restrict__ qn,
    const float* __restrict__ kn, const int* __restrict__ pos_arr, int K, int N, int Nm, int noff,
    int rows_per_b, int b_stride, int row_off) {
  __shared__ __align__(16) unsigned short Al[128 * 32];
  __shared__ __align__(16) unsigned short Bl[128 * 32];
  __shared__ float red[4][64];
  const int m0 = blockIdx.x * 128, n0 = blockIdx.y * 128;
  const int t = threadIdx.x, l = t & 63, w = t >> 6;
  const int lg = l >> 4, li = l & 15;
  const int sr = t >> 2, ss = t & 3;

  auto amap = [&](int m) -> size_t {
    return (size_t)(m / rows_per_b) * b_stride + row_off + (m % rows_per_b);
  };
  const unsigned short* ap0 = A + amap(m0 + sr) * K + ss * 8;
  const unsigned short* ap1 = A + amap(m0 + sr + 64) * K + ss * 8;
  const unsigned short* bp0 = Bt + (size_t)(n0 + sr) * K + ss * 8;
  const unsigned short* bp1 = bp0 + (size_t)64 * K;

  v4f acc[4][4] = {};

  for (int k0 = 0; k0 < K; k0 += 32) {
    async16(ap0, (char*)Al + w * 1024);
    async16(ap1, (char*)Al + w * 1024 + 4096);
    async16(bp0, (char*)Bl + w * 1024);
    async16(bp1, (char*)Bl + w * 1024 + 4096);
    ap0 += 32; ap1 += 32; bp0 += 32; bp1 += 32;
    __syncthreads();
    v8s af[4], bf[4];
#pragma unroll
    for (int mf = 0; mf < 4; mf++) {
      const int row = (w >> 1) * 64 + mf * 16 + li;
      af[mf] = *reinterpret_cast<const v8s*>((char*)Al + row * 64 + lg * 16);
    }
#pragma unroll
    for (int nf = 0; nf < 4; nf++) {
      const int row = (w & 1) * 64 + nf * 16 + li;
      bf[nf] = *reinterpret_cast<const v8s*>((char*)Bl + row * 64 + lg * 16);
    }
#pragma unroll
    for (int mf = 0; mf < 4; mf++)
#pragma unroll
      for (int nf = 0; nf < 4; nf++)
        acc[mf][nf] = mfma16(af[mf], bf[nf], acc[mf][nf]);
    __syncthreads();
  }

  const int colh = (w & 1) * 64;  // this wave's 64-column half within the tile
  // bias (for MODE 1 this is pre-norm, per reference)
#pragma unroll
  for (int nf = 0; nf < 4; nf++) {
    const float bv = bias[n0 + colh + nf * 16 + li];
#pragma unroll
    for (int mf = 0; mf < 4; mf++)
#pragma unroll
      for (int r = 0; r < 4; r++) acc[mf][nf][r] += bv;
  }

  if (MODE == 0) {
#pragma unroll
    for (int mf = 0; mf < 4; mf++) {
      const int row = m0 + (w >> 1) * 64 + mf * 16 + lg * 4;
#pragma unroll
      for (int nf = 0; nf < 4; nf++) {
        const int col = n0 + colh + nf * 16 + li;
#pragma unroll
        for (int r = 0; r < 4; r++) Cout[(size_t)(row + r) * N + col] = acc[mf][nf][r];
      }
    }
    return;
  }

  // ---- MODE 1 fused epilogue ----
  const int sec = n0 >> 11;         // 0=Q, 1=K, 2=V
  const int h = (n0 >> 7) & 15;
  const int mrow0 = m0 + (w >> 1) * 64;

  if (sec < 2) {
    // per-row sum of squares over the full 128 channels
    float ss_[4][4];
#pragma unroll
    for (int mf = 0; mf < 4; mf++)
#pragma unroll
      for (int r = 0; r < 4; r++) {
        float s = 0.f;
#pragma unroll
        for (int nf = 0; nf < 4; nf++) s += acc[mf][nf][r] * acc[mf][nf][r];
#pragma unroll
        for (int off = 1; off < 16; off <<= 1) s += __shfl_xor(s, off, 64);
        ss_[mf][r] = s;
      }
    if (li == 0) {
#pragma unroll
      for (int mf = 0; mf < 4; mf++)
#pragma unroll
        for (int r = 0; r < 4; r++) red[w][mf * 16 + lg * 4 + r] = ss_[mf][r];
    }
    __syncthreads();
    const float* gw = (sec == 0) ? qn : kn;
    unsigned short* Out = (sec == 0) ? Qb : Kb;
    float g[4];
#pragma unroll
    for (int nf = 0; nf < 4; nf++) g[nf] = gw[colh + nf * 16 + li];
#pragma unroll
    for (int mf = 0; mf < 4; mf++) {
#pragma unroll
      for (int r = 0; r < 4; r++) {
        const int m = mrow0 + mf * 16 + lg * 4 + r;
        const float tot = ss_[mf][r] + red[w ^ 1][mf * 16 + lg * 4 + r];
        const float rn = rsqrtf(tot * (1.0f / 128.0f) + 1e-6f);
        float vv[4];
#pragma unroll
        for (int nf = 0; nf < 4; nf++) vv[nf] = acc[mf][nf][r] * rn * g[nf];
        if (colh) {  // upper 64 channels: rope. pair (64+i, 96+i), i = nf*16+li, nf in {0,1}
          const float pos = (float)pos_arr[m];
#pragma unroll
          for (int nf = 0; nf < 2; nf++) {
            const float fi = (float)(nf * 16 + li);
            float sv, cv;
            sincosf(pos * expf(fi * -0.2878231366f), &sv, &cv);  // ln(1e4)/32
            const float v1 = vv[nf], v2 = vv[nf + 2];
            vv[nf] = v1 * cv - v2 * sv;
            vv[nf + 2] = v2 * cv + v1 * sv;
          }
        }
        const int b = m / Nm, n = m - b * Nm;
        const size_t base = ((size_t)(b * 16 + h) * 2560 + noff + n) * 128 + colh;
#pragma unroll
        for (int nf = 0; nf < 4; nf++) Out[base + nf * 16 + li] = f2bf(vv[nf]);
      }
    }
  } else {
    // V: write transposed [bh][128][2560]
#pragma unroll
    for (int mf = 0; mf < 4; mf++) {
      const int m = mrow0 + mf * 16 + lg * 4;  // r=0 row; 4-row run stays within one b
      const int b = m / Nm, n = m - b * Nm;
#pragma unroll
      for (int nf = 0; nf < 4; nf++) {
        const int chan = colh + nf * 16 + li;
        ushort4 o;
        o.x = f2bf(acc[mf][nf][0]); o.y = f2bf(acc[mf][nf][1]);
        o.z = f2bf(acc[mf][nf][2]); o.w = f2bf(acc[mf][nf][3]);
        *reinterpret_cast<ushort4*>(
            &Vt[((size_t)(b * 16 + h) * 128 + chan) * 2560 + noff + n]) = o;
      }
    }
  }
}

// ---------------- flash attention ----------------
// grid (20, 16, 2), block 256. Q,K: [bh][2560][128] bf16; Vt: [bh][128][2560] bf16.
// Out Ob: [b][2560][2048] bf16.
__global__ __launch_bounds__(256) void k_attn(const unsigned short* __restrict__ Qb,
                                              const unsigned short* __restrict__ Kb,
                                              const unsigned short* __restrict__ Vt,
                                              unsigned short* __restrict__ Ob) {
  __shared__ __align__(16) unsigned short Kl[64 * 128];
  __shared__ __align__(16) unsigned short Vl[128 * 64];
  __shared__ __align__(16) unsigned short Pl[4 * 32 * 64];
  const int NT = 2560;
  const float SC = 0.08838834764831845f;
  const int qt = blockIdx.x, h = blockIdx.y, b = blockIdx.z;
  const int bh = b * 16 + h;
  const int t = threadIdx.x, l = t & 63, w = t >> 6;
  const int lg = l >> 4, li = l & 15;
  const unsigned short* Qbase = Qb + ((size_t)bh * NT + qt * 128) * 128;
  const unsigned short* Kbase = Kb + (size_t)bh * NT * 128;
  const unsigned short* Vbase = Vt + (size_t)bh * 128 * NT;

  v8s qf[2][4];
#pragma unroll
  for (int mg = 0; mg < 2; mg++) {
    const int row = w * 32 + mg * 16 + li;
#pragma unroll
    for (int ds = 0; ds < 4; ds++)
      qf[mg][ds] = *reinterpret_cast<const v8s*>(Qbase + (size_t)row * 128 + (lg + ds * 4) * 8);
  }

  float m_[2][4], ls[2][4];
  v4f O_[2][8] = {};
#pragma unroll
  for (int mg = 0; mg < 2; mg++)
#pragma unroll
    for (int r = 0; r < 4; r++) { m_[mg][r] = -3.0e38f; ls[mg][r] = 0.0f; }

  const int srow = t >> 4, ssl = t & 15;
  const int vrow = t >> 3, vsl = t & 7;

  for (int kv = 0; kv < NT / 64; kv++) {
    __syncthreads();
#pragma unroll
    for (int p = 0; p < 4; p++) {
      const int row = srow + p * 16;
      v8s kv8 = *reinterpret_cast<const v8s*>(Kbase + (size_t)(kv * 64 + row) * 128 + ssl * 8);
      *reinterpret_cast<v8s*>((char*)Kl + row * 256 + ((ssl ^ (row & 7)) * 16)) = kv8;
    }
#pragma unroll
    for (int p = 0; p < 4; p++) {
      const int d = vrow + p * 32;
      v8s vv8 = *reinterpret_cast<const v8s*>(Vbase + (size_t)d * NT + kv * 64 + vsl * 8);
      *reinterpret_cast<v8s*>((char*)Vl + d * 128 + ((vsl ^ (d & 7)) * 16)) = vv8;
    }
    __syncthreads();

    v4f s[2][4] = {};
#pragma unroll
    for (int kf = 0; kf < 4; kf++) {
      const int key = kf * 16 + li;
#pragma unroll
      for (int ds = 0; ds < 4; ds++) {
        v8s bfr = *reinterpret_cast<const v8s*>(
            (char*)Kl + key * 256 + (((lg + ds * 4) ^ (key & 7)) * 16));
        s[0][kf] = mfma16(qf[0][ds], bfr, s[0][kf]);
        s[1][kf] = mfma16(qf[1][ds], bfr, s[1][kf]);
      }
    }

#pragma unroll
    for (int mg = 0; mg < 2; mg++) {
      float tm[4] = {-3.0e38f, -3.0e38f, -3.0e38f, -3.0e38f};
#pragma unroll
      for (int kf = 0; kf < 4; kf++)
#pragma unroll
        for (int r = 0; r < 4; r++) {
          s[mg][kf][r] *= SC;
          tm[r] = fmaxf(tm[r], s[mg][kf][r]);
        }
      float al[4];
#pragma unroll
      for (int r = 0; r < 4; r++) {
#pragma unroll
        for (int off = 1; off < 16; off <<= 1) tm[r] = fmaxf(tm[r], __shfl_xor(tm[r], off, 64));
        const float mn = fmaxf(m_[mg][r], tm[r]);
        al[r] = __expf(m_[mg][r] - mn);
        m_[mg][r] = mn;
      }
      float ps[4] = {0.f, 0.f, 0.f, 0.f};
#pragma unroll
      for (int kf = 0; kf < 4; kf++)
#pragma unroll
        for (int r = 0; r < 4; r++) {
          const float p = __expf(s[mg][kf][r] - m_[mg][r]);
          s[mg][kf][r] = p;
          ps[r] += p;
        }
#pragma unroll
      for (int r = 0; r < 4; r++) {
#pragma unroll
        for (int off = 1; off < 16; off <<= 1) ps[r] += __shfl_xor(ps[r], off, 64);
        ls[mg][r] = ls[mg][r] * al[r] + ps[r];
      }
#pragma unroll
      for (int df = 0; df < 8; df++)
#pragma unroll
        for (int r = 0; r < 4; r++) O_[mg][df][r] *= al[r];
#pragma unroll
      for (int kf = 0; kf < 4; kf++)
#pragma unroll
        for (int r = 0; r < 4; r++) {
          const int prow = mg * 16 + lg * 4 + r;
          const int pcol = kf * 16 + li;
          *reinterpret_cast<unsigned short*>((char*)Pl + w * 4096 + prow * 128 +
                                             (((pcol >> 3) ^ (prow & 7)) * 16) + (pcol & 7) * 2) =
              f2bf(s[mg][kf][r]);
        }
    }
    asm volatile("s_waitcnt lgkmcnt(0)" ::: "memory");
#pragma unroll
    for (int ks = 0; ks < 2; ks++) {
      v8s pa[2];
#pragma unroll
      for (int mg = 0; mg < 2; mg++) {
        const int prow = mg * 16 + li;
        pa[mg] = *reinterpret_cast<const v8s*>((char*)Pl + w * 4096 + prow * 128 +
                                               (((lg + ks * 4) ^ (prow & 7)) * 16));
      }
#pragma unroll
      for (int df = 0; df < 8; df++) {
        const int d = df * 16 + li;
        v8s vb = *reinterpret_cast<const v8s*>((char*)Vl + d * 128 + (((lg + ks * 4) ^ (d & 7)) * 16));
        O_[0][df] = mfma16(pa[0], vb, O_[0][df]);
        O_[1][df] = mfma16(pa[1], vb, O_[1][df]);
      }
    }
  }

#pragma unroll
  for (int mg = 0; mg < 2; mg++) {
    float inv[4];
#pragma unroll
    for (int r = 0; r < 4; r++) inv[r] = 1.0f / ls[mg][r];
#pragma unroll
    for (int df = 0; df < 8; df++) {
      const int d = df * 16 + li;
#pragma unroll
      for (int r = 0; r < 4; r++) {
        const int q = qt * 128 + w * 32 + mg * 16 + lg * 4 + r;
        Ob[((size_t)b * NT + q) * 2048 + h * 128 + d] = f2bf(O_[mg][df][r] * inv[r]);
      }
    }
  }
}

// ---------------- host ----------------
extern "C" void kernel_launch(void* const* d_in, const int* in_sizes, int n_in,
                              void* d_out, int out_size, void* d_ws, size_t ws_size,
                              hipStream_t stream) {
  (void)in_sizes; (void)n_in; (void)out_size;
  const float* x = (const float*)d_in[0];
  const float* y = (const float*)d_in[1];
  const int* tpos = (const int*)d_in[2];
  const int* ypos = (const int*)d_in[3];
  const float* Wqkv_x = (const float*)d_in[4];
  const float* bqkv_x = (const float*)d_in[5];
  const float* qnx = (const float*)d_in[6];
  const float* knx = (const float*)d_in[7];
  const float* Wproj_x = (const float*)d_in[8];
  const float* bproj_x = (const float*)d_in[9];
  const float* Wqkv_y = (const float*)d_in[10];
  const float* bqkv_y = (const float*)d_in[11];
  const float* qny = (const float*)d_in[12];
  const float* kny = (const float*)d_in[13];
  const float* Wproj_y = (const float*)d_in[14];
  const float* bproj_y = (const float*)d_in[15];
  float* outp = (float*)d_out;

  char* ws = (char*)d_ws;
  size_t off = 0;
  auto alloc = [&](size_t b) {
    char* p = ws + off;
    off += (b + 255) & ~(size_t)255;
    return p;
  };
  unsigned short* Wt = (unsigned short*)alloc(6144ull * 2048 * 2);   // 25.2 MB, reused x4
  unsigned short* xb = (unsigned short*)alloc(4096ull * 2048 * 2);   // 16.8 MB
  unsigned short* yb = (unsigned short*)alloc(1024ull * 2048 * 2);   //  4.2 MB
  unsigned short* Qbf = (unsigned short*)alloc(2ull * 16 * 2560 * 128 * 2);  // 21 MB
  unsigned short* Kbf = (unsigned short*)alloc(2ull * 16 * 2560 * 128 * 2);  // 21 MB
  unsigned short* Vtb = (unsigned short*)alloc(2ull * 16 * 128 * 2560 * 2);  // 21 MB
  unsigned short* Obf = (unsigned short*)alloc(2ull * 2560 * 2048 * 2);      // 21 MB
  // peak workspace ~130 MB
  if (ws_size < off) return;  // diagnostic guard: clean numeric failure instead of GPU fault

  k_f32_to_bf16<<<8192, 256, 0, stream>>>(x, xb, 2097152);
  k_f32_to_bf16<<<2048, 256, 0, stream>>>(y, yb, 524288);

  // --- x qkv ---
  k_transpose<<<dim3(32, 96), 256, 0, stream>>>(Wqkv_x, Wt, 2048, 6144);
  k_gemm<1><<<dim3(32, 48), 256, 0, stream>>>(xb, Wt, bqkv_x, nullptr, Qbf, Kbf, Vtb, qnx, knx,
                                              tpos, 2048, 6144, 2048, 0, 4096, 0, 0);
  // --- y qkv ---
  k_transpose<<<dim3(32, 96), 256, 0, stream>>>(Wqkv_y, Wt, 2048, 6144);
  k_gemm<1><<<dim3(8, 48), 256, 0, stream>>>(yb, Wt, bqkv_y, nullptr, Qbf, Kbf, Vtb, qny, kny,
                                             ypos, 2048, 6144, 512, 2048, 1024, 0, 0);

  k_attn<<<dim3(20, 16, 2), 256, 0, stream>>>(Qbf, Kbf, Vtb, Obf);

  // --- projections ---
  k_transpose<<<dim3(32, 32), 256, 0, stream>>>(Wproj_x, Wt, 2048, 2048);
  k_gemm<0><<<dim3(32, 16), 256, 0, stream>>>(Obf, Wt, bproj_x, outp, nullptr, nullptr, nullptr,
                                              nullptr, nullptr, nullptr, 2048, 2048, 0, 0, 2048,
                                              2560, 0);
  k_transpose<<<dim3(32, 32), 256, 0, stream>>>(Wproj_y, Wt, 2048, 2048);
  k_gemm<0><<<dim3(8, 16), 256, 0, stream>>>(Obf, Wt, bproj_y, outp + 8388608ull, nullptr, nullptr,
                                             nullptr, nullptr, nullptr, nullptr, 2048, 2048, 0, 0,
                                             512, 2560, 2048);
}

// Round 4
// 610.506 us; speedup vs baseline: 1.2610x; 1.2610x over previous
//
#include <hip/hip_runtime.h>
#include <stdint.h>

typedef __attribute__((ext_vector_type(8))) short v8s;
typedef __attribute__((ext_vector_type(4))) float v4f;

#define DEV static __device__ __forceinline__

DEV unsigned short f2bf(float f) {
  union { float f; unsigned int u; } v; v.f = f;
  unsigned int u = v.u;
  return (unsigned short)((u + 0x7fffu + ((u >> 16) & 1u)) >> 16);
}

DEV v4f mfma16(v8s a, v8s b, v4f c) {
  return __builtin_amdgcn_mfma_f32_16x16x32_bf16(a, b, c, 0, 0, 0);
}

DEV void async16(const void* g, void* lds) {
  __builtin_amdgcn_global_load_lds((const __attribute__((address_space(1))) unsigned int*)g,
                                   (__attribute__((address_space(3))) unsigned int*)lds,
                                   16, 0, 0);
}

// ---------------- elementwise f32 -> bf16 ----------------
__global__ __launch_bounds__(256) void k_f32_to_bf16(const float* __restrict__ in,
                                                     unsigned short* __restrict__ out, int n4) {
  int i = blockIdx.x * 256 + threadIdx.x;
  if (i < n4) {
    float4 v = reinterpret_cast<const float4*>(in)[i];
    ushort4 o;
    o.x = f2bf(v.x); o.y = f2bf(v.y); o.z = f2bf(v.z); o.w = f2bf(v.w);
    reinterpret_cast<ushort4*>(out)[i] = o;
  }
}

// ---------------- transpose+convert: in [R][C] f32 -> out [C][R] bf16 ----------------
__global__ __launch_bounds__(256) void k_transpose(const float* __restrict__ in,
                                                   unsigned short* __restrict__ out, int R, int C) {
  __shared__ float tile[64][65];
  const int r0 = blockIdx.x * 64, c0 = blockIdx.y * 64;
  const int t = threadIdx.x;
  const int rl = t >> 4, cl = (t & 15) * 4;
#pragma unroll
  for (int p = 0; p < 4; p++) {
    const int r = rl + p * 16;
    float4 v = *reinterpret_cast<const float4*>(&in[(size_t)(r0 + r) * C + c0 + cl]);
    tile[r][cl] = v.x; tile[r][cl + 1] = v.y; tile[r][cl + 2] = v.z; tile[r][cl + 3] = v.w;
  }
  __syncthreads();
  const int cw = t >> 4, rw = (t & 15) * 4;
#pragma unroll
  for (int p = 0; p < 4; p++) {
    const int c = cw + p * 16;
    ushort4 o;
    o.x = f2bf(tile[rw + 0][c]); o.y = f2bf(tile[rw + 1][c]);
    o.z = f2bf(tile[rw + 2][c]); o.w = f2bf(tile[rw + 3][c]);
    *reinterpret_cast<ushort4*>(&out[(size_t)(c0 + c) * R + r0 + rw]) = o;
  }
}

// ---------------- GEMM 128x128 tile, BK=32, bf16 MFMA, f32 accum ----------------
template <int MODE>
__global__ __launch_bounds__(256) void k_gemm(
    const unsigned short* __restrict__ A, const unsigned short* __restrict__ Bt,
    const float* __restrict__ bias, float* __restrict__ Cout,
    unsigned short* __restrict__ Qb, unsigned short* __restrict__ Kb,
    unsigned short* __restrict__ Vt, const float* __restrict__ qn,
    const float* __restrict__ kn, const int* __restrict__ pos_arr, int K, int N, int Nm, int noff,
    int rows_per_b, int b_stride, int row_off) {
  __shared__ __align__(16) unsigned short Al[128 * 32];
  __shared__ __align__(16) unsigned short Bl[128 * 32];
  __shared__ float red[4][64];
  const int m0 = blockIdx.x * 128, n0 = blockIdx.y * 128;
  const int t = threadIdx.x, l = t & 63, w = t >> 6;
  const int lg = l >> 4, li = l & 15;
  const int sr = t >> 2, ss = t & 3;

  auto amap = [&](int m) -> size_t {
    return (size_t)(m / rows_per_b) * b_stride + row_off + (m % rows_per_b);
  };
  const unsigned short* ap0 = A + amap(m0 + sr) * K + ss * 8;
  const unsigned short* ap1 = A + amap(m0 + sr + 64) * K + ss * 8;
  const unsigned short* bp0 = Bt + (size_t)(n0 + sr) * K + ss * 8;
  const unsigned short* bp1 = bp0 + (size_t)64 * K;

  v4f acc[4][4] = {};

  for (int k0 = 0; k0 < K; k0 += 32) {
    async16(ap0, (char*)Al + w * 1024);
    async16(ap1, (char*)Al + w * 1024 + 4096);
    async16(bp0, (char*)Bl + w * 1024);
    async16(bp1, (char*)Bl + w * 1024 + 4096);
    ap0 += 32; ap1 += 32; bp0 += 32; bp1 += 32;
    __syncthreads();
    v8s af[4], bf[4];
#pragma unroll
    for (int mf = 0; mf < 4; mf++) {
      const int row = (w >> 1) * 64 + mf * 16 + li;
      af[mf] = *reinterpret_cast<const v8s*>((char*)Al + row * 64 + lg * 16);
    }
#pragma unroll
    for (int nf = 0; nf < 4; nf++) {
      const int row = (w & 1) * 64 + nf * 16 + li;
      bf[nf] = *reinterpret_cast<const v8s*>((char*)Bl + row * 64 + lg * 16);
    }
#pragma unroll
    for (int mf = 0; mf < 4; mf++)
#pragma unroll
      for (int nf = 0; nf < 4; nf++)
        acc[mf][nf] = mfma16(af[mf], bf[nf], acc[mf][nf]);
    __syncthreads();
  }

  const int colh = (w & 1) * 64;
#pragma unroll
  for (int nf = 0; nf < 4; nf++) {
    const float bv = bias[n0 + colh + nf * 16 + li];
#pragma unroll
    for (int mf = 0; mf < 4; mf++)
#pragma unroll
      for (int r = 0; r < 4; r++) acc[mf][nf][r] += bv;
  }

  if (MODE == 0) {
#pragma unroll
    for (int mf = 0; mf < 4; mf++) {
      const int row = m0 + (w >> 1) * 64 + mf * 16 + lg * 4;
#pragma unroll
      for (int nf = 0; nf < 4; nf++) {
        const int col = n0 + colh + nf * 16 + li;
#pragma unroll
        for (int r = 0; r < 4; r++) Cout[(size_t)(row + r) * N + col] = acc[mf][nf][r];
      }
    }
    return;
  }

  // ---- MODE 1 fused qkv epilogue ----
  const int sec = n0 >> 11;  // 0=Q, 1=K, 2=V
  const int h = (n0 >> 7) & 15;
  const int mrow0 = m0 + (w >> 1) * 64;

  if (sec < 2) {
    float ss_[4][4];
#pragma unroll
    for (int mf = 0; mf < 4; mf++)
#pragma unroll
      for (int r = 0; r < 4; r++) {
        float s = 0.f;
#pragma unroll
        for (int nf = 0; nf < 4; nf++) s += acc[mf][nf][r] * acc[mf][nf][r];
#pragma unroll
        for (int off = 1; off < 16; off <<= 1) s += __shfl_xor(s, off, 64);
        ss_[mf][r] = s;
      }
    if (li == 0) {
#pragma unroll
      for (int mf = 0; mf < 4; mf++)
#pragma unroll
        for (int r = 0; r < 4; r++) red[w][mf * 16 + lg * 4 + r] = ss_[mf][r];
    }
    __syncthreads();
    const float* gw = (sec == 0) ? qn : kn;
    unsigned short* Out = (sec == 0) ? Qb : Kb;
    float g[4];
#pragma unroll
    for (int nf = 0; nf < 4; nf++) g[nf] = gw[colh + nf * 16 + li];
#pragma unroll
    for (int mf = 0; mf < 4; mf++) {
#pragma unroll
      for (int r = 0; r < 4; r++) {
        const int m = mrow0 + mf * 16 + lg * 4 + r;
        const float tot = ss_[mf][r] + red[w ^ 1][mf * 16 + lg * 4 + r];
        const float rn = rsqrtf(tot * (1.0f / 128.0f) + 1e-6f);
        float vv[4];
#pragma unroll
        for (int nf = 0; nf < 4; nf++) vv[nf] = acc[mf][nf][r] * rn * g[nf];
        if (colh) {
          const float pos = (float)pos_arr[m];
#pragma unroll
          for (int nf = 0; nf < 2; nf++) {
            const float fi = (float)(nf * 16 + li);
            float sv, cv;
            sincosf(pos * expf(fi * -0.2878231366f), &sv, &cv);
            const float v1 = vv[nf], v2 = vv[nf + 2];
            vv[nf] = v1 * cv - v2 * sv;
            vv[nf + 2] = v2 * cv + v1 * sv;
          }
        }
        const int b = m / Nm, n = m - b * Nm;
        const size_t base = ((size_t)(b * 16 + h) * 2560 + noff + n) * 128 + colh;
#pragma unroll
        for (int nf = 0; nf < 4; nf++) Out[base + nf * 16 + li] = f2bf(vv[nf]);
      }
    }
  } else {
#pragma unroll
    for (int mf = 0; mf < 4; mf++) {
      const int m = mrow0 + mf * 16 + lg * 4;
      const int b = m / Nm, n = m - b * Nm;
#pragma unroll
      for (int nf = 0; nf < 4; nf++) {
        const int chan = colh + nf * 16 + li;
        ushort4 o;
        o.x = f2bf(acc[mf][nf][0]); o.y = f2bf(acc[mf][nf][1]);
        o.z = f2bf(acc[mf][nf][2]); o.w = f2bf(acc[mf][nf][3]);
        *reinterpret_cast<ushort4*>(
            &Vt[((size_t)(b * 16 + h) * 128 + chan) * 2560 + noff + n]) = o;
      }
    }
  }
}

// ---------------- flash attention (fixed-max softmax, dbuf K/V, async staging) ----------------
// grid (20, 16, 2), block 256. Q,K: [bh][2560][128] bf16; Vt: [bh][128][2560] bf16.
// KVBLK=32, double-buffered. LDS: K 2x8KB + V 2x8KB + P 16KB = 48KB.
// Fixed softmax max M=12: after rmsnorm |q|=|k|=sqrt(128) so |s*SC| <= 128*0.0884 = 11.32 < 12.
__global__ __launch_bounds__(256) void k_attn(const unsigned short* __restrict__ Qb,
                                              const unsigned short* __restrict__ Kb,
                                              const unsigned short* __restrict__ Vt,
                                              unsigned short* __restrict__ Ob) {
  __shared__ __align__(16) unsigned short Kl[2 * 32 * 128];  // 16KB  [buf][row][128ch]
  __shared__ __align__(16) unsigned short Vl[2 * 128 * 32];  // 16KB  [buf][d][32keys]
  __shared__ __align__(16) unsigned short Pl[4 * 2048];      // 16KB  per-wave 32q x 32k (128B row)
  const int NT = 2560;
  const float SC = 0.08838834764831845f;
  const float FM = 12.0f;
  const int qt = blockIdx.x, h = blockIdx.y, b = blockIdx.z;
  const int bh = b * 16 + h;
  const int t = threadIdx.x, l = t & 63, w = t >> 6;
  const int lg = l >> 4, li = l & 15;
  const unsigned short* Qbase = Qb + ((size_t)bh * NT + qt * 128) * 128;
  const unsigned short* Kbase = Kb + (size_t)bh * NT * 128;
  const unsigned short* Vbase = Vt + (size_t)bh * 128 * NT;

  v8s qf[2][4];
#pragma unroll
  for (int mg = 0; mg < 2; mg++) {
    const int row = w * 32 + mg * 16 + li;
#pragma unroll
    for (int ds = 0; ds < 4; ds++)
      qf[mg][ds] = *reinterpret_cast<const v8s*>(Qbase + (size_t)row * 128 + (lg + ds * 4) * 8);
  }

  // stage K tile tt (32 rows x 256B) into buffer bf; pre-swizzled global source, linear LDS dest
  auto stageK = [&](int bf, int tt) {
#pragma unroll
    for (int p = 0; p < 2; p++) {
      const int row = w * 4 + (l >> 4) + p * 16;
      const char* g = (const char*)Kbase + ((size_t)(tt * 32 + row)) * 256 +
                      (((l & 15) ^ (row & 7)) * 16);
      async16(g, (char*)Kl + bf * 8192 + w * 1024 + p * 4096);
    }
  };
  // stage V tile tt (128 d-rows x 64B) into buffer bf
  auto stageV = [&](int bf, int tt) {
#pragma unroll
    for (int p = 0; p < 2; p++) {
      const int d = w * 16 + (l >> 2) + p * 64;
      const char* g = (const char*)Vbase + (size_t)d * (NT * 2) + (size_t)tt * 64 +
                      (((l & 3) ^ (d & 3)) * 16);
      async16(g, (char*)Vl + bf * 8192 + w * 1024 + p * 4096);
    }
  };

  float ps[2][4] = {};
  v4f O_[2][8] = {};

  stageK(0, 0);
  stageV(0, 0);
  __syncthreads();  // drains vmcnt: buffer 0 ready

  const int NTILES = NT / 32;  // 80
  for (int tt = 0; tt < NTILES; tt++) {
    const int bf = tt & 1;
    if (tt + 1 < NTILES) {  // prefetch next tile into other buffer (overlaps compute)
      stageK(bf ^ 1, tt + 1);
      stageV(bf ^ 1, tt + 1);
    }

    // ---- QK^T: 32 queries x 32 keys per wave ----
    v4f s[2][2] = {};
#pragma unroll
    for (int kf = 0; kf < 2; kf++) {
      const int key = kf * 16 + li;
#pragma unroll
      for (int ds = 0; ds < 4; ds++) {
        v8s bfr = *reinterpret_cast<const v8s*>(
            (char*)Kl + bf * 8192 + key * 256 + (((lg + ds * 4) ^ (key & 7)) * 16));
        s[0][kf] = mfma16(qf[0][ds], bfr, s[0][kf]);
        s[1][kf] = mfma16(qf[1][ds], bfr, s[1][kf]);
      }
    }

    // ---- fixed-max softmax + P write ----
#pragma unroll
    for (int mg = 0; mg < 2; mg++)
#pragma unroll
      for (int kf = 0; kf < 2; kf++)
#pragma unroll
        for (int r = 0; r < 4; r++) {
          const float p = __expf(fmaf(s[mg][kf][r], SC, -FM));
          ps[mg][r] += p;
          const int prow = mg * 16 + lg * 4 + r;
          const int bq = kf * 2 + (li >> 3);
          *reinterpret_cast<unsigned short*>((char*)Pl + w * 4096 + prow * 128 +
                                             ((bq ^ (prow & 7)) * 16) + (li & 7) * 2) = f2bf(p);
        }
    asm volatile("s_waitcnt lgkmcnt(0)" ::: "memory");

    // ---- PV ----
    v8s pa[2];
#pragma unroll
    for (int mg = 0; mg < 2; mg++) {
      const int prow = mg * 16 + li;
      pa[mg] = *reinterpret_cast<const v8s*>((char*)Pl + w * 4096 + prow * 128 +
                                             ((lg ^ (prow & 7)) * 16));
    }
#pragma unroll
    for (int df = 0; df < 8; df++) {
      const int d = df * 16 + li;
      v8s vb = *reinterpret_cast<const v8s*>(
          (char*)Vl + bf * 8192 + d * 64 + ((lg ^ (d & 3)) * 16));
      O_[0][df] = mfma16(pa[0], vb, O_[0][df]);
      O_[1][df] = mfma16(pa[1], vb, O_[1][df]);
    }
    __syncthreads();  // prefetch landed; all waves done with buf before it is overwritten
  }

  // ---- final denominator reduce + store ----
#pragma unroll
  for (int mg = 0; mg < 2; mg++)
#pragma unroll
    for (int r = 0; r < 4; r++) {
#pragma unroll
      for (int off = 1; off < 16; off <<= 1) ps[mg][r] += __shfl_xor(ps[mg][r], off, 64);
    }
#pragma unroll
  for (int mg = 0; mg < 2; mg++) {
    float inv[4];
#pragma unroll
    for (int r = 0; r < 4; r++) inv[r] = 1.0f / ps[mg][r];
#pragma unroll
    for (int df = 0; df < 8; df++) {
      const int d = df * 16 + li;
#pragma unroll
      for (int r = 0; r < 4; r++) {
        const int q = qt * 128 + w * 32 + mg * 16 + lg * 4 + r;
        Ob[((size_t)b * NT + q) * 2048 + h * 128 + d] = f2bf(O_[mg][df][r] * inv[r]);
      }
    }
  }
}

// ---------------- host ----------------
extern "C" void kernel_launch(void* const* d_in, const int* in_sizes, int n_in,
                              void* d_out, int out_size, void* d_ws, size_t ws_size,
                              hipStream_t stream) {
  (void)in_sizes; (void)n_in; (void)out_size;
  const float* x = (const float*)d_in[0];
  const float* y = (const float*)d_in[1];
  const int* tpos = (const int*)d_in[2];
  const int* ypos = (const int*)d_in[3];
  const float* Wqkv_x = (const float*)d_in[4];
  const float* bqkv_x = (const float*)d_in[5];
  const float* qnx = (const float*)d_in[6];
  const float* knx = (const float*)d_in[7];
  const float* Wproj_x = (const float*)d_in[8];
  const float* bproj_x = (const float*)d_in[9];
  const float* Wqkv_y = (const float*)d_in[10];
  const float* bqkv_y = (const float*)d_in[11];
  const float* qny = (const float*)d_in[12];
  const float* kny = (const float*)d_in[13];
  const float* Wproj_y = (const float*)d_in[14];
  const float* bproj_y = (const float*)d_in[15];
  float* outp = (float*)d_out;

  char* ws = (char*)d_ws;
  size_t off = 0;
  auto alloc = [&](size_t b) {
    char* p = ws + off;
    off += (b + 255) & ~(size_t)255;
    return p;
  };
  unsigned short* Wt = (unsigned short*)alloc(6144ull * 2048 * 2);
  unsigned short* xb = (unsigned short*)alloc(4096ull * 2048 * 2);
  unsigned short* yb = (unsigned short*)alloc(1024ull * 2048 * 2);
  unsigned short* Qbf = (unsigned short*)alloc(2ull * 16 * 2560 * 128 * 2);
  unsigned short* Kbf = (unsigned short*)alloc(2ull * 16 * 2560 * 128 * 2);
  unsigned short* Vtb = (unsigned short*)alloc(2ull * 16 * 128 * 2560 * 2);
  unsigned short* Obf = (unsigned short*)alloc(2ull * 2560 * 2048 * 2);
  if (ws_size < off) return;

  k_f32_to_bf16<<<8192, 256, 0, stream>>>(x, xb, 2097152);
  k_f32_to_bf16<<<2048, 256, 0, stream>>>(y, yb, 524288);

  k_transpose<<<dim3(32, 96), 256, 0, stream>>>(Wqkv_x, Wt, 2048, 6144);
  k_gemm<1><<<dim3(32, 48), 256, 0, stream>>>(xb, Wt, bqkv_x, nullptr, Qbf, Kbf, Vtb, qnx, knx,
                                              tpos, 2048, 6144, 2048, 0, 4096, 0, 0);
  k_transpose<<<dim3(32, 96), 256, 0, stream>>>(Wqkv_y, Wt, 2048, 6144);
  k_gemm<1><<<dim3(8, 48), 256, 0, stream>>>(yb, Wt, bqkv_y, nullptr, Qbf, Kbf, Vtb, qny, kny,
                                             ypos, 2048, 6144, 512, 2048, 1024, 0, 0);

  k_attn<<<dim3(20, 16, 2), 256, 0, stream>>>(Qbf, Kbf, Vtb, Obf);

  k_transpose<<<dim3(32, 32), 256, 0, stream>>>(Wproj_x, Wt, 2048, 2048);
  k_gemm<0><<<dim3(32, 16), 256, 0, stream>>>(Obf, Wt, bproj_x, outp, nullptr, nullptr, nullptr,
                                              nullptr, nullptr, nullptr, 2048, 2048, 0, 0, 2048,
                                              2560, 0);
  k_transpose<<<dim3(32, 32), 256, 0, stream>>>(Wproj_y, Wt, 2048, 2048);
  k_gemm<0><<<dim3(8, 16), 256, 0, stream>>>(Obf, Wt, bproj_y, outp + 8388608ull, nullptr, nullptr,
                                             nullptr, nullptr, nullptr, nullptr, 2048, 2048, 0, 0,
                                             512, 2560, 2048);
}

// Round 7
// 605.707 us; speedup vs baseline: 1.2710x; 1.0079x over previous
//
#include <hip/hip_runtime.h>
#include <stdint.h>

typedef __attribute__((ext_vector_type(8))) short v8s;
typedef __attribute__((ext_vector_type(4))) float v4f;

#define DEV static __device__ __forceinline__

DEV unsigned short f2bf(float f) {
  union { float f; unsigned int u; } v; v.f = f;
  unsigned int u = v.u;
  return (unsigned short)((u + 0x7fffu + ((u >> 16) & 1u)) >> 16);
}

DEV v4f mfma16(v8s a, v8s b, v4f c) {
  return __builtin_amdgcn_mfma_f32_16x16x32_bf16(a, b, c, 0, 0, 0);
}

DEV unsigned int cvtpk(float lo, float hi) {
  unsigned int r;
  asm("v_cvt_pk_bf16_f32 %0, %1, %2" : "=v"(r) : "v"(lo), "v"(hi));
  return r;
}

DEV void async16(const void* g, void* lds) {
  __builtin_amdgcn_global_load_lds((const __attribute__((address_space(1))) unsigned int*)g,
                                   (__attribute__((address_space(3))) unsigned int*)lds,
                                   16, 0, 0);
}

// ---------------- elementwise f32 -> bf16 ----------------
__global__ __launch_bounds__(256) void k_f32_to_bf16(const float* __restrict__ in,
                                                     unsigned short* __restrict__ out, int n4) {
  int i = blockIdx.x * 256 + threadIdx.x;
  if (i < n4) {
    float4 v = reinterpret_cast<const float4*>(in)[i];
    ushort4 o;
    o.x = f2bf(v.x); o.y = f2bf(v.y); o.z = f2bf(v.z); o.w = f2bf(v.w);
    reinterpret_cast<ushort4*>(out)[i] = o;
  }
}

// ---------------- transpose+convert: in [R][C] f32 -> out [C][R] bf16 ----------------
__global__ __launch_bounds__(256) void k_transpose(const float* __restrict__ in,
                                                   unsigned short* __restrict__ out, int R, int C) {
  __shared__ float tile[64][65];
  const int r0 = blockIdx.x * 64, c0 = blockIdx.y * 64;
  const int t = threadIdx.x;
  const int rl = t >> 4, cl = (t & 15) * 4;
#pragma unroll
  for (int p = 0; p < 4; p++) {
    const int r = rl + p * 16;
    float4 v = *reinterpret_cast<const float4*>(&in[(size_t)(r0 + r) * C + c0 + cl]);
    tile[r][cl] = v.x; tile[r][cl + 1] = v.y; tile[r][cl + 2] = v.z; tile[r][cl + 3] = v.w;
  }
  __syncthreads();
  const int cw = t >> 4, rw = (t & 15) * 4;
#pragma unroll
  for (int p = 0; p < 4; p++) {
    const int c = cw + p * 16;
    ushort4 o;
    o.x = f2bf(tile[rw + 0][c]); o.y = f2bf(tile[rw + 1][c]);
    o.z = f2bf(tile[rw + 2][c]); o.w = f2bf(tile[rw + 3][c]);
    *reinterpret_cast<ushort4*>(&out[(size_t)(c0 + c) * R + r0 + rw]) = o;
  }
}

// ---------------- GEMM 128x128 tile, BK=32, bf16 MFMA, f32 accum ----------------
// MODE 0: Cout = A*Bt^T + bias (row amap). MODE 1: fused qkv epilogue:
//   q,k: rmsnorm+rope -> [bh][2560][128]; v: -> [bh][kb=80][128][32] (kv-blocked transposed)
template <int MODE>
__global__ __launch_bounds__(256) void k_gemm(
    const unsigned short* __restrict__ A, const unsigned short* __restrict__ Bt,
    const float* __restrict__ bias, float* __restrict__ Cout,
    unsigned short* __restrict__ Qb, unsigned short* __restrict__ Kb,
    unsigned short* __restrict__ Vt, const float* __restrict__ qn,
    const float* __restrict__ kn, const int* __restrict__ pos_arr, int K, int N, int Nm, int noff,
    int rows_per_b, int b_stride, int row_off) {
  __shared__ __align__(16) unsigned short Al[128 * 32];
  __shared__ __align__(16) unsigned short Bl[128 * 32];
  __shared__ float red[4][64];
  const int m0 = blockIdx.x * 128, n0 = blockIdx.y * 128;
  const int t = threadIdx.x, l = t & 63, w = t >> 6;
  const int lg = l >> 4, li = l & 15;
  const int sr = t >> 2, ss = t & 3;

  auto amap = [&](int m) -> size_t {
    return (size_t)(m / rows_per_b) * b_stride + row_off + (m % rows_per_b);
  };
  const unsigned short* ap0 = A + amap(m0 + sr) * K + ss * 8;
  const unsigned short* ap1 = A + amap(m0 + sr + 64) * K + ss * 8;
  const unsigned short* bp0 = Bt + (size_t)(n0 + sr) * K + ss * 8;
  const unsigned short* bp1 = bp0 + (size_t)64 * K;

  v4f acc[4][4] = {};

  for (int k0 = 0; k0 < K; k0 += 32) {
    async16(ap0, (char*)Al + w * 1024);
    async16(ap1, (char*)Al + w * 1024 + 4096);
    async16(bp0, (char*)Bl + w * 1024);
    async16(bp1, (char*)Bl + w * 1024 + 4096);
    ap0 += 32; ap1 += 32; bp0 += 32; bp1 += 32;
    __syncthreads();
    v8s af[4], bf[4];
#pragma unroll
    for (int mf = 0; mf < 4; mf++) {
      const int row = (w >> 1) * 64 + mf * 16 + li;
      af[mf] = *reinterpret_cast<const v8s*>((char*)Al + row * 64 + lg * 16);
    }
#pragma unroll
    for (int nf = 0; nf < 4; nf++) {
      const int row = (w & 1) * 64 + nf * 16 + li;
      bf[nf] = *reinterpret_cast<const v8s*>((char*)Bl + row * 64 + lg * 16);
    }
#pragma unroll
    for (int mf = 0; mf < 4; mf++)
#pragma unroll
      for (int nf = 0; nf < 4; nf++)
        acc[mf][nf] = mfma16(af[mf], bf[nf], acc[mf][nf]);
    __syncthreads();
  }

  const int colh = (w & 1) * 64;
#pragma unroll
  for (int nf = 0; nf < 4; nf++) {
    const float bv = bias[n0 + colh + nf * 16 + li];
#pragma unroll
    for (int mf = 0; mf < 4; mf++)
#pragma unroll
      for (int r = 0; r < 4; r++) acc[mf][nf][r] += bv;
  }

  if (MODE == 0) {
#pragma unroll
    for (int mf = 0; mf < 4; mf++) {
      const int row = m0 + (w >> 1) * 64 + mf * 16 + lg * 4;
#pragma unroll
      for (int nf = 0; nf < 4; nf++) {
        const int col = n0 + colh + nf * 16 + li;
#pragma unroll
        for (int r = 0; r < 4; r++) Cout[(size_t)(row + r) * N + col] = acc[mf][nf][r];
      }
    }
    return;
  }

  // ---- MODE 1 fused qkv epilogue ----
  const int sec = n0 >> 11;  // 0=Q, 1=K, 2=V
  const int h = (n0 >> 7) & 15;
  const int mrow0 = m0 + (w >> 1) * 64;

  if (sec < 2) {
    float ss_[4][4];
#pragma unroll
    for (int mf = 0; mf < 4; mf++)
#pragma unroll
      for (int r = 0; r < 4; r++) {
        float s = 0.f;
#pragma unroll
        for (int nf = 0; nf < 4; nf++) s += acc[mf][nf][r] * acc[mf][nf][r];
#pragma unroll
        for (int off = 1; off < 16; off <<= 1) s += __shfl_xor(s, off, 64);
        ss_[mf][r] = s;
      }
    if (li == 0) {
#pragma unroll
      for (int mf = 0; mf < 4; mf++)
#pragma unroll
        for (int r = 0; r < 4; r++) red[w][mf * 16 + lg * 4 + r] = ss_[mf][r];
    }
    __syncthreads();
    const float* gw = (sec == 0) ? qn : kn;
    unsigned short* Out = (sec == 0) ? Qb : Kb;
    float g[4];
#pragma unroll
    for (int nf = 0; nf < 4; nf++) g[nf] = gw[colh + nf * 16 + li];
#pragma unroll
    for (int mf = 0; mf < 4; mf++) {
#pragma unroll
      for (int r = 0; r < 4; r++) {
        const int m = mrow0 + mf * 16 + lg * 4 + r;
        const float tot = ss_[mf][r] + red[w ^ 1][mf * 16 + lg * 4 + r];
        const float rn = rsqrtf(tot * (1.0f / 128.0f) + 1e-6f);
        float vv[4];
#pragma unroll
        for (int nf = 0; nf < 4; nf++) vv[nf] = acc[mf][nf][r] * rn * g[nf];
        if (colh) {
          const float pos = (float)pos_arr[m];
#pragma unroll
          for (int nf = 0; nf < 2; nf++) {
            const float fi = (float)(nf * 16 + li);
            float sv, cv;
            sincosf(pos * expf(fi * -0.2878231366f), &sv, &cv);
            const float v1 = vv[nf], v2 = vv[nf + 2];
            vv[nf] = v1 * cv - v2 * sv;
            vv[nf + 2] = v2 * cv + v1 * sv;
          }
        }
        const int b = m / Nm, n = m - b * Nm;
        const size_t base = ((size_t)(b * 16 + h) * 2560 + noff + n) * 128 + colh;
#pragma unroll
        for (int nf = 0; nf < 4; nf++) Out[base + nf * 16 + li] = f2bf(vv[nf]);
      }
    }
  } else {
    // V: write kv-blocked transposed [bh][kb][128 chan][32 keys]
#pragma unroll
    for (int mf = 0; mf < 4; mf++) {
      const int m = mrow0 + mf * 16 + lg * 4;  // 4-row run (keys), multiple of 4
      const int b = m / Nm, n = m - b * Nm;
      const int key = noff + n;
      const size_t base = ((size_t)(b * 16 + h) * 80 + (key >> 5)) * 4096 + (key & 31);
#pragma unroll
      for (int nf = 0; nf < 4; nf++) {
        const int chan = colh + nf * 16 + li;
        ushort4 o;
        o.x = f2bf(acc[mf][nf][0]); o.y = f2bf(acc[mf][nf][1]);
        o.z = f2bf(acc[mf][nf][2]); o.w = f2bf(acc[mf][nf][3]);
        *reinterpret_cast<ushort4*>(&Vt[base + chan * 32]) = o;
      }
    }
  }
}

// ---------------- flash attention ----------------
// grid (20, 16, 2), block 256. Q,K: [bh][2560][128] bf16; Vt: [bh][80][128][32] bf16.
// Swapped QK^T with in-tile key permutation kappa(rho) so each lane's P values are
// exactly the 16x16x32 A-fragment k-slots (keys lg*8..lg*8+7). PV uses the proven
// mfma_f32_16x16x32_bf16 only. Fixed-max softmax (|s*SC| <= 11.4 < 12).
__global__ __launch_bounds__(256) void k_attn(const unsigned short* __restrict__ Qb,
                                              const unsigned short* __restrict__ Kb,
                                              const unsigned short* __restrict__ Vt,
                                              unsigned short* __restrict__ Ob) {
  __shared__ __align__(16) unsigned short Kl[2 * 32 * 128];  // 16KB [buf][row][128ch]
  __shared__ __align__(16) unsigned short Vl[2 * 128 * 32];  // 16KB [buf][d][32keys]
  const int NT = 2560;
  const float SC = 0.08838834764831845f;
  const float FM = 12.0f;
  const int qt = blockIdx.x, h = blockIdx.y, b = blockIdx.z;
  const int bh = b * 16 + h;
  const int t = threadIdx.x, l = t & 63, w = t >> 6;
  const int lg = l >> 4, li = l & 15;
  const unsigned short* Qbase = Qb + ((size_t)bh * NT + qt * 128) * 128;
  const unsigned short* Kbase = Kb + (size_t)bh * NT * 128;
  const unsigned short* Vbase = Vt + (size_t)bh * 327680;

  v8s qf[2][4];
#pragma unroll
  for (int mg = 0; mg < 2; mg++) {
    const int row = w * 32 + mg * 16 + li;
#pragma unroll
    for (int ds = 0; ds < 4; ds++)
      qf[mg][ds] = *reinterpret_cast<const v8s*>(Qbase + (size_t)row * 128 + (lg + ds * 4) * 8);
  }

  // K staging with in-tile key permutation: LDS row rho holds global key kappa(rho),
  // kappa(rho) = ((rho>>2)&3)*8 + ((rho>>4)&1)*4 + (rho&3)  (bit shuffle, bijective).
  auto stageK = [&](int bf2, int tt) {
#pragma unroll
    for (int p = 0; p < 2; p++) {
      const int rho = w * 4 + (l >> 4) + p * 16;
      const int key = ((rho >> 2) & 3) * 8 + ((rho >> 4) & 1) * 4 + (rho & 3);
      const char* g = (const char*)Kbase + ((size_t)(tt * 32 + key)) * 256 +
                      (((l & 15) ^ (rho & 7)) * 16);
      async16(g, (char*)Kl + bf2 * 8192 + w * 1024 + p * 4096);
    }
  };
  // V staging: LDS granule j of row d holds source granule j^(d&6) (8B granules).
  auto stageV = [&](int bf2, int tt) {
#pragma unroll
    for (int p = 0; p < 2; p++) {
      const int d = w * 32 + p * 16 + (l >> 2);
      const char* g = (const char*)Vbase + (size_t)tt * 8192 + d * 64 +
                      ((((l & 3) * 2) ^ (d & 6)) * 8);
      async16(g, (char*)Vl + bf2 * 8192 + w * 2048 + p * 1024);
    }
  };

  float ps[2] = {0.f, 0.f};
  v4f O_[2][8] = {};

  stageK(0, 0);
  stageV(0, 0);
  __syncthreads();

  for (int tt = 0; tt < 80; tt++) {
    const int bf2 = tt & 1;
    if (tt + 1 < 80) {
      stageK(bf2 ^ 1, tt + 1);
      stageV(bf2 ^ 1, tt + 1);
    }

    // ---- swapped QK^T: s[mg][kf][r] = score(q = mg*16+li, key = lg*8 + kf*4 + r) ----
    v4f s[2][2] = {};
#pragma unroll
    for (int kf = 0; kf < 2; kf++) {
      const int row = kf * 16 + li;  // LDS storage row
#pragma unroll
      for (int ds = 0; ds < 4; ds++) {
        v8s ka = *reinterpret_cast<const v8s*>(
            (char*)Kl + bf2 * 8192 + row * 256 + (((lg + ds * 4) ^ (row & 7)) * 16));
        s[0][kf] = mfma16(ka, qf[0][ds], s[0][kf]);
        s[1][kf] = mfma16(ka, qf[1][ds], s[1][kf]);
      }
    }

    // ---- fixed-max softmax; pack per-lane keys lg*8..lg*8+7 into one v8s A-fragment ----
    v8s pa[2];
#pragma unroll
    for (int mg = 0; mg < 2; mg++) {
      float p[2][4];
#pragma unroll
      for (int kf = 0; kf < 2; kf++)
#pragma unroll
        for (int r = 0; r < 4; r++) {
          p[kf][r] = __expf(fmaf(s[mg][kf][r], SC, -FM));
          ps[mg] += p[kf][r];
        }
      union { v8s v; unsigned int u[4]; } pk;
      pk.u[0] = cvtpk(p[0][0], p[0][1]);
      pk.u[1] = cvtpk(p[0][2], p[0][3]);
      pk.u[2] = cvtpk(p[1][0], p[1][1]);
      pk.u[3] = cvtpk(p[1][2], p[1][3]);
      pa[mg] = pk.v;
    }

    // ---- PV: O[q][d] += P * V via 16x16x32; B-fragment = V[keys lg*8..+7][d=li] ----
#pragma unroll
    for (int df = 0; df < 8; df++) {
      const int d = df * 16 + li;
      v8s vb = *reinterpret_cast<const v8s*>(
          (char*)Vl + bf2 * 8192 + d * 64 + (((lg * 2) ^ (d & 6)) * 8));
      O_[0][df] = mfma16(pa[0], vb, O_[0][df]);
      O_[1][df] = mfma16(pa[1], vb, O_[1][df]);
    }
    __syncthreads();
  }

  // ---- denominator: sum partials across lg lanes, redistribute to output rows ----
#pragma unroll
  for (int mg = 0; mg < 2; mg++) {
    ps[mg] += __shfl_xor(ps[mg], 16, 64);
    ps[mg] += __shfl_xor(ps[mg], 32, 64);
  }
#pragma unroll
  for (int mg = 0; mg < 2; mg++) {
    float inv[4];
#pragma unroll
    for (int r = 0; r < 4; r++) inv[r] = 1.0f / __shfl(ps[mg], lg * 4 + r, 64);
#pragma unroll
    for (int df = 0; df < 8; df++) {
      const int d = df * 16 + li;
#pragma unroll
      for (int r = 0; r < 4; r++) {
        const int q = qt * 128 + w * 32 + mg * 16 + lg * 4 + r;
        Ob[((size_t)b * NT + q) * 2048 + h * 128 + d] = f2bf(O_[mg][df][r] * inv[r]);
      }
    }
  }
}

// ---------------- host ----------------
extern "C" void kernel_launch(void* const* d_in, const int* in_sizes, int n_in,
                              void* d_out, int out_size, void* d_ws, size_t ws_size,
                              hipStream_t stream) {
  (void)in_sizes; (void)n_in; (void)out_size;
  const float* x = (const float*)d_in[0];
  const float* y = (const float*)d_in[1];
  const int* tpos = (const int*)d_in[2];
  const int* ypos = (const int*)d_in[3];
  const float* Wqkv_x = (const float*)d_in[4];
  const float* bqkv_x = (const float*)d_in[5];
  const float* qnx = (const float*)d_in[6];
  const float* knx = (const float*)d_in[7];
  const float* Wproj_x = (const float*)d_in[8];
  const float* bproj_x = (const float*)d_in[9];
  const float* Wqkv_y = (const float*)d_in[10];
  const float* bqkv_y = (const float*)d_in[11];
  const float* qny = (const float*)d_in[12];
  const float* kny = (const float*)d_in[13];
  const float* Wproj_y = (const float*)d_in[14];
  const float* bproj_y = (const float*)d_in[15];
  float* outp = (float*)d_out;

  char* ws = (char*)d_ws;
  size_t off = 0;
  auto alloc = [&](size_t b) {
    char* p = ws + off;
    off += (b + 255) & ~(size_t)255;
    return p;
  };
  unsigned short* Wt = (unsigned short*)alloc(6144ull * 2048 * 2);
  unsigned short* xb = (unsigned short*)alloc(4096ull * 2048 * 2);
  unsigned short* yb = (unsigned short*)alloc(1024ull * 2048 * 2);
  unsigned short* Qbf = (unsigned short*)alloc(2ull * 16 * 2560 * 128 * 2);
  unsigned short* Kbf = (unsigned short*)alloc(2ull * 16 * 2560 * 128 * 2);
  unsigned short* Vtb = (unsigned short*)alloc(2ull * 16 * 80 * 128 * 32 * 2);
  unsigned short* Obf = (unsigned short*)alloc(2ull * 2560 * 2048 * 2);
  if (ws_size < off) return;

  k_f32_to_bf16<<<8192, 256, 0, stream>>>(x, xb, 2097152);
  k_f32_to_bf16<<<2048, 256, 0, stream>>>(y, yb, 524288);

  k_transpose<<<dim3(32, 96), 256, 0, stream>>>(Wqkv_x, Wt, 2048, 6144);
  k_gemm<1><<<dim3(32, 48), 256, 0, stream>>>(xb, Wt, bqkv_x, nullptr, Qbf, Kbf, Vtb, qnx, knx,
                                              tpos, 2048, 6144, 2048, 0, 4096, 0, 0);
  k_transpose<<<dim3(32, 96), 256, 0, stream>>>(Wqkv_y, Wt, 2048, 6144);
  k_gemm<1><<<dim3(8, 48), 256, 0, stream>>>(yb, Wt, bqkv_y, nullptr, Qbf, Kbf, Vtb, qny, kny,
                                             ypos, 2048, 6144, 512, 2048, 1024, 0, 0);

  k_attn<<<dim3(20, 16, 2), 256, 0, stream>>>(Qbf, Kbf, Vtb, Obf);

  k_transpose<<<dim3(32, 32), 256, 0, stream>>>(Wproj_x, Wt, 2048, 2048);
  k_gemm<0><<<dim3(32, 16), 256, 0, stream>>>(Obf, Wt, bproj_x, outp, nullptr, nullptr, nullptr,
                                              nullptr, nullptr, nullptr, 2048, 2048, 0, 0, 2048,
                                              2560, 0);
  k_transpose<<<dim3(32, 32), 256, 0, stream>>>(Wproj_y, Wt, 2048, 2048);
  k_gemm<0><<<dim3(8, 16), 256, 0, stream>>>(Obf, Wt, bproj_y, outp + 8388608ull, nullptr, nullptr,
                                             nullptr, nullptr, nullptr, nullptr, 2048, 2048, 0, 0,
                                             512, 2560, 2048);
}

// Round 8
// 593.787 us; speedup vs baseline: 1.2965x; 1.0201x over previous
//
#include <hip/hip_runtime.h>
#include <stdint.h>

typedef __attribute__((ext_vector_type(8))) short v8s;
typedef __attribute__((ext_vector_type(4))) float v4f;

#define DEV static __device__ __forceinline__

DEV unsigned short f2bf(float f) {
  union { float f; unsigned int u; } v; v.f = f;
  unsigned int u = v.u;
  return (unsigned short)((u + 0x7fffu + ((u >> 16) & 1u)) >> 16);
}

DEV v4f mfma16(v8s a, v8s b, v4f c) {
  return __builtin_amdgcn_mfma_f32_16x16x32_bf16(a, b, c, 0, 0, 0);
}

DEV unsigned int cvtpk(float lo, float hi) {
  unsigned int r;
  asm("v_cvt_pk_bf16_f32 %0, %1, %2" : "=v"(r) : "v"(lo), "v"(hi));
  return r;
}

DEV void async16(const void* g, void* lds) {
  __builtin_amdgcn_global_load_lds((const __attribute__((address_space(1))) unsigned int*)g,
                                   (__attribute__((address_space(3))) unsigned int*)lds,
                                   16, 0, 0);
}

// ---------------- elementwise f32 -> bf16 ----------------
__global__ __launch_bounds__(256) void k_f32_to_bf16(const float* __restrict__ in,
                                                     unsigned short* __restrict__ out, int n4) {
  int i = blockIdx.x * 256 + threadIdx.x;
  if (i < n4) {
    float4 v = reinterpret_cast<const float4*>(in)[i];
    ushort4 o;
    o.x = f2bf(v.x); o.y = f2bf(v.y); o.z = f2bf(v.z); o.w = f2bf(v.w);
    reinterpret_cast<ushort4*>(out)[i] = o;
  }
}

// ---------------- rope table: tbl[row][i] = {cos,sin}(pos[row] * 10000^(-i/32)) ----------------
__global__ __launch_bounds__(256) void k_rope_tbl(const int* __restrict__ pos,
                                                  float* __restrict__ tbl, int nrows) {
  int idx = blockIdx.x * 256 + threadIdx.x;
  if (idx < nrows * 32) {
    int row = idx >> 5, i = idx & 31;
    float ang = (float)pos[row] * expf((float)i * -0.2878231366f);  // ln(1e4)/32
    float sv, cv;
    sincosf(ang, &sv, &cv);
    reinterpret_cast<float2*>(tbl)[(size_t)row * 32 + i] = make_float2(cv, sv);
  }
}

// ---------------- transpose+convert: in [R][C] f32 -> out [C][R] bf16 ----------------
__global__ __launch_bounds__(256) void k_transpose(const float* __restrict__ in,
                                                   unsigned short* __restrict__ out, int R, int C) {
  __shared__ float tile[64][65];
  const int r0 = blockIdx.x * 64, c0 = blockIdx.y * 64;
  const int t = threadIdx.x;
  const int rl = t >> 4, cl = (t & 15) * 4;
#pragma unroll
  for (int p = 0; p < 4; p++) {
    const int r = rl + p * 16;
    float4 v = *reinterpret_cast<const float4*>(&in[(size_t)(r0 + r) * C + c0 + cl]);
    tile[r][cl] = v.x; tile[r][cl + 1] = v.y; tile[r][cl + 2] = v.z; tile[r][cl + 3] = v.w;
  }
  __syncthreads();
  const int cw = t >> 4, rw = (t & 15) * 4;
#pragma unroll
  for (int p = 0; p < 4; p++) {
    const int c = cw + p * 16;
    ushort4 o;
    o.x = f2bf(tile[rw + 0][c]); o.y = f2bf(tile[rw + 1][c]);
    o.z = f2bf(tile[rw + 2][c]); o.w = f2bf(tile[rw + 3][c]);
    *reinterpret_cast<ushort4*>(&out[(size_t)(c0 + c) * R + r0 + rw]) = o;
  }
}

// ---------------- GEMM 128x128 tile, BK=32, bf16 MFMA, f32 accum ----------------
// MODE 0: Cout = A*Bt^T + bias (row amap). MODE 1: fused qkv epilogue:
//   q,k: rmsnorm+rope(table) -> [bh][2560][128]; v: -> [bh][80][128][32] kv-blocked transposed
template <int MODE>
__global__ __launch_bounds__(256) void k_gemm(
    const unsigned short* __restrict__ A, const unsigned short* __restrict__ Bt,
    const float* __restrict__ bias, float* __restrict__ Cout,
    unsigned short* __restrict__ Qb, unsigned short* __restrict__ Kb,
    unsigned short* __restrict__ Vt, const float* __restrict__ qn,
    const float* __restrict__ kn, const float* __restrict__ rtbl, int K, int N, int Nm, int noff,
    int rows_per_b, int b_stride, int row_off) {
  __shared__ __align__(16) unsigned short Al[128 * 32];
  __shared__ __align__(16) unsigned short Bl[128 * 32];
  __shared__ float red[4][64];
  const int m0 = blockIdx.x * 128, n0 = blockIdx.y * 128;
  const int t = threadIdx.x, l = t & 63, w = t >> 6;
  const int lg = l >> 4, li = l & 15;
  const int sr = t >> 2, ss = t & 3;

  auto amap = [&](int m) -> size_t {
    return (size_t)(m / rows_per_b) * b_stride + row_off + (m % rows_per_b);
  };
  const unsigned short* ap0 = A + amap(m0 + sr) * K + ss * 8;
  const unsigned short* ap1 = A + amap(m0 + sr + 64) * K + ss * 8;
  const unsigned short* bp0 = Bt + (size_t)(n0 + sr) * K + ss * 8;
  const unsigned short* bp1 = bp0 + (size_t)64 * K;

  v4f acc[4][4] = {};

  for (int k0 = 0; k0 < K; k0 += 32) {
    async16(ap0, (char*)Al + w * 1024);
    async16(ap1, (char*)Al + w * 1024 + 4096);
    async16(bp0, (char*)Bl + w * 1024);
    async16(bp1, (char*)Bl + w * 1024 + 4096);
    ap0 += 32; ap1 += 32; bp0 += 32; bp1 += 32;
    __syncthreads();
    v8s af[4], bf[4];
#pragma unroll
    for (int mf = 0; mf < 4; mf++) {
      const int row = (w >> 1) * 64 + mf * 16 + li;
      af[mf] = *reinterpret_cast<const v8s*>((char*)Al + row * 64 + lg * 16);
    }
#pragma unroll
    for (int nf = 0; nf < 4; nf++) {
      const int row = (w & 1) * 64 + nf * 16 + li;
      bf[nf] = *reinterpret_cast<const v8s*>((char*)Bl + row * 64 + lg * 16);
    }
#pragma unroll
    for (int mf = 0; mf < 4; mf++)
#pragma unroll
      for (int nf = 0; nf < 4; nf++)
        acc[mf][nf] = mfma16(af[mf], bf[nf], acc[mf][nf]);
    __syncthreads();
  }

  const int colh = (w & 1) * 64;
#pragma unroll
  for (int nf = 0; nf < 4; nf++) {
    const float bv = bias[n0 + colh + nf * 16 + li];
#pragma unroll
    for (int mf = 0; mf < 4; mf++)
#pragma unroll
      for (int r = 0; r < 4; r++) acc[mf][nf][r] += bv;
  }

  if (MODE == 0) {
#pragma unroll
    for (int mf = 0; mf < 4; mf++) {
      const int row = m0 + (w >> 1) * 64 + mf * 16 + lg * 4;
#pragma unroll
      for (int nf = 0; nf < 4; nf++) {
        const int col = n0 + colh + nf * 16 + li;
#pragma unroll
        for (int r = 0; r < 4; r++) Cout[(size_t)(row + r) * N + col] = acc[mf][nf][r];
      }
    }
    return;
  }

  // ---- MODE 1 fused qkv epilogue ----
  const int sec = n0 >> 11;  // 0=Q, 1=K, 2=V
  const int h = (n0 >> 7) & 15;
  const int mrow0 = m0 + (w >> 1) * 64;

  if (sec < 2) {
    float ss_[4][4];
#pragma unroll
    for (int mf = 0; mf < 4; mf++)
#pragma unroll
      for (int r = 0; r < 4; r++) {
        float s = 0.f;
#pragma unroll
        for (int nf = 0; nf < 4; nf++) s += acc[mf][nf][r] * acc[mf][nf][r];
#pragma unroll
        for (int off = 1; off < 16; off <<= 1) s += __shfl_xor(s, off, 64);
        ss_[mf][r] = s;
      }
    if (li == 0) {
#pragma unroll
      for (int mf = 0; mf < 4; mf++)
#pragma unroll
        for (int r = 0; r < 4; r++) red[w][mf * 16 + lg * 4 + r] = ss_[mf][r];
    }
    __syncthreads();
    const float* gw = (sec == 0) ? qn : kn;
    unsigned short* Out = (sec == 0) ? Qb : Kb;
    float g[4];
#pragma unroll
    for (int nf = 0; nf < 4; nf++) g[nf] = gw[colh + nf * 16 + li];
#pragma unroll
    for (int mf = 0; mf < 4; mf++) {
#pragma unroll
      for (int r = 0; r < 4; r++) {
        const int m = mrow0 + mf * 16 + lg * 4 + r;
        const float tot = ss_[mf][r] + red[w ^ 1][mf * 16 + lg * 4 + r];
        const float rn = rsqrtf(tot * (1.0f / 128.0f) + 1e-6f);
        float vv[4];
#pragma unroll
        for (int nf = 0; nf < 4; nf++) vv[nf] = acc[mf][nf][r] * rn * g[nf];
        if (colh) {  // upper 64 channels: rope from table. pair (64+i, 96+i), i = nf*16+li
#pragma unroll
          for (int nf = 0; nf < 2; nf++) {
            const float2 cs = reinterpret_cast<const float2*>(rtbl)[(size_t)m * 32 + nf * 16 + li];
            const float v1 = vv[nf], v2 = vv[nf + 2];
            vv[nf] = v1 * cs.x - v2 * cs.y;
            vv[nf + 2] = v2 * cs.x + v1 * cs.y;
          }
        }
        const int b = m / Nm, n = m - b * Nm;
        const size_t base = ((size_t)(b * 16 + h) * 2560 + noff + n) * 128 + colh;
#pragma unroll
        for (int nf = 0; nf < 4; nf++) Out[base + nf * 16 + li] = f2bf(vv[nf]);
      }
    }
  } else {
    // V: write kv-blocked transposed [bh][kb][128 chan][32 keys]
#pragma unroll
    for (int mf = 0; mf < 4; mf++) {
      const int m = mrow0 + mf * 16 + lg * 4;  // 4-row run (keys), multiple of 4
      const int b = m / Nm, n = m - b * Nm;
      const int key = noff + n;
      const size_t base = ((size_t)(b * 16 + h) * 80 + (key >> 5)) * 4096 + (key & 31);
#pragma unroll
      for (int nf = 0; nf < 4; nf++) {
        const int chan = colh + nf * 16 + li;
        ushort4 o;
        o.x = f2bf(acc[mf][nf][0]); o.y = f2bf(acc[mf][nf][1]);
        o.z = f2bf(acc[mf][nf][2]); o.w = f2bf(acc[mf][nf][3]);
        *reinterpret_cast<ushort4*>(&Vt[base + chan * 32]) = o;
      }
    }
  }
}

// ---------------- flash attention ----------------
// grid 640 (1-D, XCD-swizzled), block 256. Q,K: [bh][2560][128]; Vt: [bh][80][128][32].
// All 20 q-tiles of one (b,h) land on one XCD: xcd=i&7 -> bh in [4*xcd, 4*xcd+4).
__global__ __launch_bounds__(256) void k_attn(const unsigned short* __restrict__ Qb,
                                              const unsigned short* __restrict__ Kb,
                                              const unsigned short* __restrict__ Vt,
                                              unsigned short* __restrict__ Ob) {
  __shared__ __align__(16) unsigned short Kl[2 * 32 * 128];  // 16KB [buf][row][128ch]
  __shared__ __align__(16) unsigned short Vl[2 * 128 * 32];  // 16KB [buf][d][32keys]
  const int NT = 2560;
  const float SC = 0.08838834764831845f;
  const float FM = 12.0f;
  const int i = blockIdx.x;
  const int xcd = i & 7, j = i >> 3;
  const int qt = j % 20;
  const int bh = xcd * 4 + j / 20;
  const int b = bh >> 4;
  const int t = threadIdx.x, l = t & 63, w = t >> 6;
  const int lg = l >> 4, li = l & 15;
  const unsigned short* Qbase = Qb + ((size_t)bh * NT + qt * 128) * 128;
  const unsigned short* Kbase = Kb + (size_t)bh * NT * 128;
  const unsigned short* Vbase = Vt + (size_t)bh * 327680;

  v8s qf[2][4];
#pragma unroll
  for (int mg = 0; mg < 2; mg++) {
    const int row = w * 32 + mg * 16 + li;
#pragma unroll
    for (int ds = 0; ds < 4; ds++)
      qf[mg][ds] = *reinterpret_cast<const v8s*>(Qbase + (size_t)row * 128 + (lg + ds * 4) * 8);
  }

  // K staging with in-tile key permutation kappa(rho)=((rho>>2)&3)*8+((rho>>4)&1)*4+(rho&3)
  auto stageK = [&](int bf2, int tt) {
#pragma unroll
    for (int p = 0; p < 2; p++) {
      const int rho = w * 4 + (l >> 4) + p * 16;
      const int key = ((rho >> 2) & 3) * 8 + ((rho >> 4) & 1) * 4 + (rho & 3);
      const char* g = (const char*)Kbase + ((size_t)(tt * 32 + key)) * 256 +
                      (((l & 15) ^ (rho & 7)) * 16);
      async16(g, (char*)Kl + bf2 * 8192 + w * 1024 + p * 4096);
    }
  };
  // V staging: LDS granule j of row d holds source granule j^(d&6) (8B granules).
  auto stageV = [&](int bf2, int tt) {
#pragma unroll
    for (int p = 0; p < 2; p++) {
      const int d = w * 32 + p * 16 + (l >> 2);
      const char* g = (const char*)Vbase + (size_t)tt * 8192 + d * 64 +
                      ((((l & 3) * 2) ^ (d & 6)) * 8);
      async16(g, (char*)Vl + bf2 * 8192 + w * 2048 + p * 1024);
    }
  };

  float ps[2] = {0.f, 0.f};
  v4f O_[2][8] = {};

  stageK(0, 0);
  stageV(0, 0);
  __syncthreads();

  for (int tt = 0; tt < 80; tt++) {
    const int bf2 = tt & 1;
    if (tt + 1 < 80) {
      stageK(bf2 ^ 1, tt + 1);
      stageV(bf2 ^ 1, tt + 1);
    }

    // ---- swapped QK^T: s[mg][kf][r] = score(q = mg*16+li, key = lg*8 + kf*4 + r) ----
    v4f s[2][2] = {};
#pragma unroll
    for (int kf = 0; kf < 2; kf++) {
      const int row = kf * 16 + li;
#pragma unroll
      for (int ds = 0; ds < 4; ds++) {
        v8s ka = *reinterpret_cast<const v8s*>(
            (char*)Kl + bf2 * 8192 + row * 256 + (((lg + ds * 4) ^ (row & 7)) * 16));
        s[0][kf] = mfma16(ka, qf[0][ds], s[0][kf]);
        s[1][kf] = mfma16(ka, qf[1][ds], s[1][kf]);
      }
    }

    // ---- fixed-max softmax; pack per-lane keys lg*8..lg*8+7 into one v8s A-fragment ----
    v8s pa[2];
#pragma unroll
    for (int mg = 0; mg < 2; mg++) {
      float p[2][4];
#pragma unroll
      for (int kf = 0; kf < 2; kf++)
#pragma unroll
        for (int r = 0; r < 4; r++) {
          p[kf][r] = __expf(fmaf(s[mg][kf][r], SC, -FM));
          ps[mg] += p[kf][r];
        }
      union { v8s v; unsigned int u[4]; } pk;
      pk.u[0] = cvtpk(p[0][0], p[0][1]);
      pk.u[1] = cvtpk(p[0][2], p[0][3]);
      pk.u[2] = cvtpk(p[1][0], p[1][1]);
      pk.u[3] = cvtpk(p[1][2], p[1][3]);
      pa[mg] = pk.v;
    }

    // ---- PV: O[q][d] += P * V via 16x16x32; B-fragment = V[keys lg*8..+7][d] ----
#pragma unroll
    for (int df = 0; df < 8; df++) {
      const int d = df * 16 + li;
      v8s vb = *reinterpret_cast<const v8s*>(
          (char*)Vl + bf2 * 8192 + d * 64 + (((lg * 2) ^ (d & 6)) * 8));
      O_[0][df] = mfma16(pa[0], vb, O_[0][df]);
      O_[1][df] = mfma16(pa[1], vb, O_[1][df]);
    }
    __syncthreads();
  }

  // ---- denominator: sum partials across lg lanes, redistribute to output rows ----
#pragma unroll
  for (int mg = 0; mg < 2; mg++) {
    ps[mg] += __shfl_xor(ps[mg], 16, 64);
    ps[mg] += __shfl_xor(ps[mg], 32, 64);
  }
#pragma unroll
  for (int mg = 0; mg < 2; mg++) {
    float inv[4];
#pragma unroll
    for (int r = 0; r < 4; r++) inv[r] = 1.0f / __shfl(ps[mg], lg * 4 + r, 64);
#pragma unroll
    for (int df = 0; df < 8; df++) {
      const int d = df * 16 + li;
#pragma unroll
      for (int r = 0; r < 4; r++) {
        const int q = qt * 128 + w * 32 + mg * 16 + lg * 4 + r;
        Ob[((size_t)b * NT + q) * 2048 + bh % 16 * 128 + d] = f2bf(O_[mg][df][r] * inv[r]);
      }
    }
  }
}

// ---------------- host ----------------
extern "C" void kernel_launch(void* const* d_in, const int* in_sizes, int n_in,
                              void* d_out, int out_size, void* d_ws, size_t ws_size,
                              hipStream_t stream) {
  (void)in_sizes; (void)n_in; (void)out_size;
  const float* x = (const float*)d_in[0];
  const float* y = (const float*)d_in[1];
  const int* tpos = (const int*)d_in[2];
  const int* ypos = (const int*)d_in[3];
  const float* Wqkv_x = (const float*)d_in[4];
  const float* bqkv_x = (const float*)d_in[5];
  const float* qnx = (const float*)d_in[6];
  const float* knx = (const float*)d_in[7];
  const float* Wproj_x = (const float*)d_in[8];
  const float* bproj_x = (const float*)d_in[9];
  const float* Wqkv_y = (const float*)d_in[10];
  const float* bqkv_y = (const float*)d_in[11];
  const float* qny = (const float*)d_in[12];
  const float* kny = (const float*)d_in[13];
  const float* Wproj_y = (const float*)d_in[14];
  const float* bproj_y = (const float*)d_in[15];
  float* outp = (float*)d_out;

  char* ws = (char*)d_ws;
  size_t off = 0;
  auto alloc = [&](size_t b) {
    char* p = ws + off;
    off += (b + 255) & ~(size_t)255;
    return p;
  };
  unsigned short* Wt = (unsigned short*)alloc(6144ull * 2048 * 2);
  unsigned short* xb = (unsigned short*)alloc(4096ull * 2048 * 2);
  unsigned short* yb = (unsigned short*)alloc(1024ull * 2048 * 2);
  unsigned short* Qbf = (unsigned short*)alloc(2ull * 16 * 2560 * 128 * 2);
  unsigned short* Kbf = (unsigned short*)alloc(2ull * 16 * 2560 * 128 * 2);
  unsigned short* Vtb = (unsigned short*)alloc(2ull * 16 * 80 * 128 * 32 * 2);
  unsigned short* Obf = (unsigned short*)alloc(2ull * 2560 * 2048 * 2);
  float* rtx = (float*)alloc(4096ull * 64 * 4);  // rope table x: [4096 rows][32][cos,sin]
  float* rty = (float*)alloc(1024ull * 64 * 4);  // rope table y
  if (ws_size < off) return;

  k_f32_to_bf16<<<8192, 256, 0, stream>>>(x, xb, 2097152);
  k_f32_to_bf16<<<2048, 256, 0, stream>>>(y, yb, 524288);
  k_rope_tbl<<<512, 256, 0, stream>>>(tpos, rtx, 4096);
  k_rope_tbl<<<128, 256, 0, stream>>>(ypos, rty, 1024);

  k_transpose<<<dim3(32, 96), 256, 0, stream>>>(Wqkv_x, Wt, 2048, 6144);
  k_gemm<1><<<dim3(32, 48), 256, 0, stream>>>(xb, Wt, bqkv_x, nullptr, Qbf, Kbf, Vtb, qnx, knx,
                                              rtx, 2048, 6144, 2048, 0, 4096, 0, 0);
  k_transpose<<<dim3(32, 96), 256, 0, stream>>>(Wqkv_y, Wt, 2048, 6144);
  k_gemm<1><<<dim3(8, 48), 256, 0, stream>>>(yb, Wt, bqkv_y, nullptr, Qbf, Kbf, Vtb, qny, kny,
                                             rty, 2048, 6144, 512, 2048, 1024, 0, 0);

  k_attn<<<640, 256, 0, stream>>>(Qbf, Kbf, Vtb, Obf);

  k_transpose<<<dim3(32, 32), 256, 0, stream>>>(Wproj_x, Wt, 2048, 2048);
  k_gemm<0><<<dim3(32, 16), 256, 0, stream>>>(Obf, Wt, bproj_x, outp, nullptr, nullptr, nullptr,
                                              nullptr, nullptr, nullptr, 2048, 2048, 0, 0, 2048,
                                              2560, 0);
  k_transpose<<<dim3(32, 32), 256, 0, stream>>>(Wproj_y, Wt, 2048, 2048);
  k_gemm<0><<<dim3(8, 16), 256, 0, stream>>>(Obf, Wt, bproj_y, outp + 8388608ull, nullptr, nullptr,
                                             nullptr, nullptr, nullptr, nullptr, 2048, 2048, 0, 0,
                                             512, 2560, 2048);
}

// Round 9
// 527.041 us; speedup vs baseline: 1.4607x; 1.1266x over previous
//
#include <hip/hip_runtime.h>
#include <stdint.h>

typedef __attribute__((ext_vector_type(8))) short v8s;
typedef __attribute__((ext_vector_type(4))) float v4f;

#define DEV static __device__ __forceinline__

DEV unsigned short f2bf(float f) {
  union { float f; unsigned int u; } v; v.f = f;
  unsigned int u = v.u;
  return (unsigned short)((u + 0x7fffu + ((u >> 16) & 1u)) >> 16);
}

DEV v4f mfma16(v8s a, v8s b, v4f c) {
  return __builtin_amdgcn_mfma_f32_16x16x32_bf16(a, b, c, 0, 0, 0);
}

DEV unsigned int cvtpk(float lo, float hi) {
  unsigned int r;
  asm("v_cvt_pk_bf16_f32 %0, %1, %2" : "=v"(r) : "v"(lo), "v"(hi));
  return r;
}

DEV void async16(const void* g, void* lds) {
  __builtin_amdgcn_global_load_lds((const __attribute__((address_space(1))) unsigned int*)g,
                                   (__attribute__((address_space(3))) unsigned int*)lds,
                                   16, 0, 0);
}

// ---------------- elementwise f32 -> bf16 ----------------
__global__ __launch_bounds__(256) void k_f32_to_bf16(const float* __restrict__ in,
                                                     unsigned short* __restrict__ out, int n4) {
  int i = blockIdx.x * 256 + threadIdx.x;
  if (i < n4) {
    float4 v = reinterpret_cast<const float4*>(in)[i];
    ushort4 o;
    o.x = f2bf(v.x); o.y = f2bf(v.y); o.z = f2bf(v.z); o.w = f2bf(v.w);
    reinterpret_cast<ushort4*>(out)[i] = o;
  }
}

// ---------------- rope table: tbl[row][i] = {cos,sin}(pos[row] * 10000^(-i/32)) ----------------
__global__ __launch_bounds__(256) void k_rope_tbl(const int* __restrict__ pos,
                                                  float* __restrict__ tbl, int nrows) {
  int idx = blockIdx.x * 256 + threadIdx.x;
  if (idx < nrows * 32) {
    int row = idx >> 5, i = idx & 31;
    float ang = (float)pos[row] * expf((float)i * -0.2878231366f);  // ln(1e4)/32
    float sv, cv;
    sincosf(ang, &sv, &cv);
    reinterpret_cast<float2*>(tbl)[(size_t)row * 32 + i] = make_float2(cv, sv);
  }
}

// ---------------- transpose+convert: in [R][C] f32 -> out [C][R] bf16 ----------------
__global__ __launch_bounds__(256) void k_transpose(const float* __restrict__ in,
                                                   unsigned short* __restrict__ out, int R, int C) {
  __shared__ float tile[64][65];
  const int r0 = blockIdx.x * 64, c0 = blockIdx.y * 64;
  const int t = threadIdx.x;
  const int rl = t >> 4, cl = (t & 15) * 4;
#pragma unroll
  for (int p = 0; p < 4; p++) {
    const int r = rl + p * 16;
    float4 v = *reinterpret_cast<const float4*>(&in[(size_t)(r0 + r) * C + c0 + cl]);
    tile[r][cl] = v.x; tile[r][cl + 1] = v.y; tile[r][cl + 2] = v.z; tile[r][cl + 3] = v.w;
  }
  __syncthreads();
  const int cw = t >> 4, rw = (t & 15) * 4;
#pragma unroll
  for (int p = 0; p < 4; p++) {
    const int c = cw + p * 16;
    ushort4 o;
    o.x = f2bf(tile[rw + 0][c]); o.y = f2bf(tile[rw + 1][c]);
    o.z = f2bf(tile[rw + 2][c]); o.w = f2bf(tile[rw + 3][c]);
    *reinterpret_cast<ushort4*>(&out[(size_t)(c0 + c) * R + r0 + rw]) = o;
  }
}

// ---------------- GEMM 128x128 tile, BK=32, bf16 MFMA, f32 accum ----------------
// MODE 0: Cout = A*Bt^T + bias (row amap). MODE 1: fused qkv epilogue:
//   q,k: rmsnorm+rope(table) -> [bh][2560][128]; v: -> [bh][80][128][32] kv-blocked transposed
template <int MODE>
__global__ __launch_bounds__(256) void k_gemm(
    const unsigned short* __restrict__ A, const unsigned short* __restrict__ Bt,
    const float* __restrict__ bias, float* __restrict__ Cout,
    unsigned short* __restrict__ Qb, unsigned short* __restrict__ Kb,
    unsigned short* __restrict__ Vt, const float* __restrict__ qn,
    const float* __restrict__ kn, const float* __restrict__ rtbl, int K, int N, int Nm, int noff,
    int rows_per_b, int b_stride, int row_off) {
  __shared__ __align__(16) unsigned short Al[128 * 32];
  __shared__ __align__(16) unsigned short Bl[128 * 32];
  __shared__ float red[4][64];
  const int m0 = blockIdx.x * 128, n0 = blockIdx.y * 128;
  const int t = threadIdx.x, l = t & 63, w = t >> 6;
  const int lg = l >> 4, li = l & 15;
  const int sr = t >> 2, ss = t & 3;

  auto amap = [&](int m) -> size_t {
    return (size_t)(m / rows_per_b) * b_stride + row_off + (m % rows_per_b);
  };
  const unsigned short* ap0 = A + amap(m0 + sr) * K + ss * 8;
  const unsigned short* ap1 = A + amap(m0 + sr + 64) * K + ss * 8;
  const unsigned short* bp0 = Bt + (size_t)(n0 + sr) * K + ss * 8;
  const unsigned short* bp1 = bp0 + (size_t)64 * K;

  v4f acc[4][4] = {};

  for (int k0 = 0; k0 < K; k0 += 32) {
    async16(ap0, (char*)Al + w * 1024);
    async16(ap1, (char*)Al + w * 1024 + 4096);
    async16(bp0, (char*)Bl + w * 1024);
    async16(bp1, (char*)Bl + w * 1024 + 4096);
    ap0 += 32; ap1 += 32; bp0 += 32; bp1 += 32;
    __syncthreads();
    v8s af[4], bf[4];
#pragma unroll
    for (int mf = 0; mf < 4; mf++) {
      const int row = (w >> 1) * 64 + mf * 16 + li;
      af[mf] = *reinterpret_cast<const v8s*>((char*)Al + row * 64 + lg * 16);
    }
#pragma unroll
    for (int nf = 0; nf < 4; nf++) {
      const int row = (w & 1) * 64 + nf * 16 + li;
      bf[nf] = *reinterpret_cast<const v8s*>((char*)Bl + row * 64 + lg * 16);
    }
#pragma unroll
    for (int mf = 0; mf < 4; mf++)
#pragma unroll
      for (int nf = 0; nf < 4; nf++)
        acc[mf][nf] = mfma16(af[mf], bf[nf], acc[mf][nf]);
    __syncthreads();
  }

  const int colh = (w & 1) * 64;
#pragma unroll
  for (int nf = 0; nf < 4; nf++) {
    const float bv = bias[n0 + colh + nf * 16 + li];
#pragma unroll
    for (int mf = 0; mf < 4; mf++)
#pragma unroll
      for (int r = 0; r < 4; r++) acc[mf][nf][r] += bv;
  }

  if (MODE == 0) {
#pragma unroll
    for (int mf = 0; mf < 4; mf++) {
      const int row = m0 + (w >> 1) * 64 + mf * 16 + lg * 4;
#pragma unroll
      for (int nf = 0; nf < 4; nf++) {
        const int col = n0 + colh + nf * 16 + li;
#pragma unroll
        for (int r = 0; r < 4; r++) Cout[(size_t)(row + r) * N + col] = acc[mf][nf][r];
      }
    }
    return;
  }

  // ---- MODE 1 fused qkv epilogue ----
  const int sec = n0 >> 11;  // 0=Q, 1=K, 2=V
  const int h = (n0 >> 7) & 15;
  const int mrow0 = m0 + (w >> 1) * 64;

  if (sec < 2) {
    float ss_[4][4];
#pragma unroll
    for (int mf = 0; mf < 4; mf++)
#pragma unroll
      for (int r = 0; r < 4; r++) {
        float s = 0.f;
#pragma unroll
        for (int nf = 0; nf < 4; nf++) s += acc[mf][nf][r] * acc[mf][nf][r];
#pragma unroll
        for (int off = 1; off < 16; off <<= 1) s += __shfl_xor(s, off, 64);
        ss_[mf][r] = s;
      }
    if (li == 0) {
#pragma unroll
      for (int mf = 0; mf < 4; mf++)
#pragma unroll
        for (int r = 0; r < 4; r++) red[w][mf * 16 + lg * 4 + r] = ss_[mf][r];
    }
    __syncthreads();
    const float* gw = (sec == 0) ? qn : kn;
    unsigned short* Out = (sec == 0) ? Qb : Kb;
    float g[4];
#pragma unroll
    for (int nf = 0; nf < 4; nf++) g[nf] = gw[colh + nf * 16 + li];
#pragma unroll
    for (int mf = 0; mf < 4; mf++) {
#pragma unroll
      for (int r = 0; r < 4; r++) {
        const int m = mrow0 + mf * 16 + lg * 4 + r;
        const float tot = ss_[mf][r] + red[w ^ 1][mf * 16 + lg * 4 + r];
        const float rn = rsqrtf(tot * (1.0f / 128.0f) + 1e-6f);
        float vv[4];
#pragma unroll
        for (int nf = 0; nf < 4; nf++) vv[nf] = acc[mf][nf][r] * rn * g[nf];
        if (colh) {  // upper 64 channels: rope from table. pair (64+i, 96+i), i = nf*16+li
#pragma unroll
          for (int nf = 0; nf < 2; nf++) {
            const float2 cs = reinterpret_cast<const float2*>(rtbl)[(size_t)m * 32 + nf * 16 + li];
            const float v1 = vv[nf], v2 = vv[nf + 2];
            vv[nf] = v1 * cs.x - v2 * cs.y;
            vv[nf + 2] = v2 * cs.x + v1 * cs.y;
          }
        }
        const int b = m / Nm, n = m - b * Nm;
        const size_t base = ((size_t)(b * 16 + h) * 2560 + noff + n) * 128 + colh;
#pragma unroll
        for (int nf = 0; nf < 4; nf++) Out[base + nf * 16 + li] = f2bf(vv[nf]);
      }
    }
  } else {
    // V: write kv-blocked transposed [bh][kb][128 chan][32 keys]
#pragma unroll
    for (int mf = 0; mf < 4; mf++) {
      const int m = mrow0 + mf * 16 + lg * 4;  // 4-row run (keys), multiple of 4
      const int b = m / Nm, n = m - b * Nm;
      const int key = noff + n;
      const size_t base = ((size_t)(b * 16 + h) * 80 + (key >> 5)) * 4096 + (key & 31);
#pragma unroll
      for (int nf = 0; nf < 4; nf++) {
        const int chan = colh + nf * 16 + li;
        ushort4 o;
        o.x = f2bf(acc[mf][nf][0]); o.y = f2bf(acc[mf][nf][1]);
        o.z = f2bf(acc[mf][nf][2]); o.w = f2bf(acc[mf][nf][3]);
        *reinterpret_cast<ushort4*>(&Vt[base + chan * 32]) = o;
      }
    }
  }
}

// ---------------- flash attention (3-deep counted-vmcnt pipeline) ----------------
// grid 640 (XCD-swizzled), block 256. Q,K: [bh][2560][128]; Vt: [bh][80][128][32].
// Per wave each stage = exactly 4 global_load_lds (2 K + 2 V). Steady state 12 in
// flight; vmcnt(8) at iter top => stage tt landed. Raw barriers, no vmcnt(0) drain.
__global__ __launch_bounds__(256) void k_attn(const unsigned short* __restrict__ Qb,
                                              const unsigned short* __restrict__ Kb,
                                              const unsigned short* __restrict__ Vt,
                                              unsigned short* __restrict__ Ob) {
  __shared__ __align__(16) char Ldss[3 * 16384];  // [buf][K 8KB | V 8KB]
  const int NT = 2560;
  const float SC = 0.08838834764831845f;
  const float FM = 12.0f;
  const int i = blockIdx.x;
  const int xcd = i & 7, j = i >> 3;
  const int qt = j % 20;
  const int bh = xcd * 4 + j / 20;
  const int b = bh >> 4, h = bh & 15;
  const int t = threadIdx.x, l = t & 63, w = t >> 6;
  const int lg = l >> 4, li = l & 15;
  const unsigned short* Qbase = Qb + ((size_t)bh * NT + qt * 128) * 128;
  const unsigned short* Kbase = Kb + (size_t)bh * NT * 128;
  const unsigned short* Vbase = Vt + (size_t)bh * 327680;

  v8s qf[2][4];
#pragma unroll
  for (int mg = 0; mg < 2; mg++) {
    const int row = w * 32 + mg * 16 + li;
#pragma unroll
    for (int ds = 0; ds < 4; ds++)
      qf[mg][ds] = *reinterpret_cast<const v8s*>(Qbase + (size_t)row * 128 + (lg + ds * 4) * 8);
  }

  // K staging with in-tile key permutation kappa(rho)=((rho>>2)&3)*8+((rho>>4)&1)*4+(rho&3)
  auto stage = [&](char* lb, int st) {
#pragma unroll
    for (int p = 0; p < 2; p++) {
      const int rho = w * 4 + (l >> 4) + p * 16;
      const int key = ((rho >> 2) & 3) * 8 + ((rho >> 4) & 1) * 4 + (rho & 3);
      const char* g = (const char*)Kbase + ((size_t)(st * 32 + key)) * 256 +
                      (((l & 15) ^ (rho & 7)) * 16);
      async16(g, lb + w * 1024 + p * 4096);
    }
#pragma unroll
    for (int p = 0; p < 2; p++) {
      const int d = w * 32 + p * 16 + (l >> 2);
      const char* g = (const char*)Vbase + (size_t)st * 8192 + d * 64 +
                      ((((l & 3) * 2) ^ (d & 6)) * 8);
      async16(g, lb + 8192 + w * 2048 + p * 1024);
    }
  };

  // hoisted LDS read byte-offsets
  int koff[2][4], voff[8];
#pragma unroll
  for (int kf = 0; kf < 2; kf++)
#pragma unroll
    for (int ds = 0; ds < 4; ds++) {
      const int row = kf * 16 + li;
      koff[kf][ds] = row * 256 + (((lg + ds * 4) ^ (row & 7)) * 16);
    }
#pragma unroll
  for (int df = 0; df < 8; df++) {
    const int d = df * 16 + li;
    voff[df] = 8192 + d * 64 + (((lg * 2) ^ (d & 6)) * 8);
  }

  float ps[2] = {0.f, 0.f};
  v4f O_[2][8] = {};

  stage(Ldss, 0);
  stage(Ldss + 16384, 1);
  stage(Ldss + 32768, 2);

  int bufc = 0;
  for (int tt = 0; tt < 80; tt++) {
    asm volatile("s_waitcnt vmcnt(8)" ::: "memory");  // stage tt landed (this wave)
    __builtin_amdgcn_sched_barrier(0);
    __builtin_amdgcn_s_barrier();  // all waves' stage tt landed
    __builtin_amdgcn_sched_barrier(0);
    char* B = Ldss + bufc;

    // ---- swapped QK^T: s[mg][kf][r] = score(q = mg*16+li, key = lg*8 + kf*4 + r) ----
    v4f s[2][2] = {};
    __builtin_amdgcn_s_setprio(1);
#pragma unroll
    for (int kf = 0; kf < 2; kf++)
#pragma unroll
      for (int ds = 0; ds < 4; ds++) {
        v8s ka = *reinterpret_cast<const v8s*>(B + koff[kf][ds]);
        s[0][kf] = mfma16(ka, qf[0][ds], s[0][kf]);
        s[1][kf] = mfma16(ka, qf[1][ds], s[1][kf]);
      }
    __builtin_amdgcn_s_setprio(0);

    // ---- fixed-max softmax; pack per-lane keys lg*8..lg*8+7 into one v8s A-fragment ----
    v8s pa[2];
#pragma unroll
    for (int mg = 0; mg < 2; mg++) {
      float p[2][4];
#pragma unroll
      for (int kf = 0; kf < 2; kf++)
#pragma unroll
        for (int r = 0; r < 4; r++) {
          p[kf][r] = __expf(fmaf(s[mg][kf][r], SC, -FM));
          ps[mg] += p[kf][r];
        }
      union { v8s v; unsigned int u[4]; } pk;
      pk.u[0] = cvtpk(p[0][0], p[0][1]);
      pk.u[1] = cvtpk(p[0][2], p[0][3]);
      pk.u[2] = cvtpk(p[1][0], p[1][1]);
      pk.u[3] = cvtpk(p[1][2], p[1][3]);
      pa[mg] = pk.v;
    }

    // ---- PV: O[q][d] += P * V via 16x16x32 ----
    __builtin_amdgcn_s_setprio(1);
#pragma unroll
    for (int df = 0; df < 8; df++) {
      v8s vb = *reinterpret_cast<const v8s*>(B + voff[df]);
      O_[0][df] = mfma16(pa[0], vb, O_[0][df]);
      O_[1][df] = mfma16(pa[1], vb, O_[1][df]);
    }
    __builtin_amdgcn_s_setprio(0);

    __builtin_amdgcn_sched_barrier(0);
    __builtin_amdgcn_s_barrier();  // all waves done reading buf tt%3
    __builtin_amdgcn_sched_barrier(0);
    const int st = (tt + 3 < 80) ? tt + 3 : 79;  // tail: reload into dead buffer
    stage(B, st);                                 // (tt+3)%3 == tt%3
    bufc += 16384;
    if (bufc == 49152) bufc = 0;
  }
  asm volatile("s_waitcnt vmcnt(0)" ::: "memory");  // drain before epilogue/exit

  // ---- denominator: sum partials across lg lanes, redistribute to output rows ----
#pragma unroll
  for (int mg = 0; mg < 2; mg++) {
    ps[mg] += __shfl_xor(ps[mg], 16, 64);
    ps[mg] += __shfl_xor(ps[mg], 32, 64);
  }
#pragma unroll
  for (int mg = 0; mg < 2; mg++) {
    float inv[4];
#pragma unroll
    for (int r = 0; r < 4; r++) inv[r] = 1.0f / __shfl(ps[mg], lg * 4 + r, 64);
#pragma unroll
    for (int df = 0; df < 8; df++) {
      const int d = df * 16 + li;
#pragma unroll
      for (int r = 0; r < 4; r++) {
        const int q = qt * 128 + w * 32 + mg * 16 + lg * 4 + r;
        Ob[((size_t)b * NT + q) * 2048 + h * 128 + d] = f2bf(O_[mg][df][r] * inv[r]);
      }
    }
  }
}

// ---------------- host ----------------
extern "C" void kernel_launch(void* const* d_in, const int* in_sizes, int n_in,
                              void* d_out, int out_size, void* d_ws, size_t ws_size,
                              hipStream_t stream) {
  (void)in_sizes; (void)n_in; (void)out_size;
  const float* x = (const float*)d_in[0];
  const float* y = (const float*)d_in[1];
  const int* tpos = (const int*)d_in[2];
  const int* ypos = (const int*)d_in[3];
  const float* Wqkv_x = (const float*)d_in[4];
  const float* bqkv_x = (const float*)d_in[5];
  const float* qnx = (const float*)d_in[6];
  const float* knx = (const float*)d_in[7];
  const float* Wproj_x = (const float*)d_in[8];
  const float* bproj_x = (const float*)d_in[9];
  const float* Wqkv_y = (const float*)d_in[10];
  const float* bqkv_y = (const float*)d_in[11];
  const float* qny = (const float*)d_in[12];
  const float* kny = (const float*)d_in[13];
  const float* Wproj_y = (const float*)d_in[14];
  const float* bproj_y = (const float*)d_in[15];
  float* outp = (float*)d_out;

  char* ws = (char*)d_ws;
  size_t off = 0;
  auto alloc = [&](size_t b) {
    char* p = ws + off;
    off += (b + 255) & ~(size_t)255;
    return p;
  };
  unsigned short* Wt = (unsigned short*)alloc(6144ull * 2048 * 2);
  unsigned short* xb = (unsigned short*)alloc(4096ull * 2048 * 2);
  unsigned short* yb = (unsigned short*)alloc(1024ull * 2048 * 2);
  unsigned short* Qbf = (unsigned short*)alloc(2ull * 16 * 2560 * 128 * 2);
  unsigned short* Kbf = (unsigned short*)alloc(2ull * 16 * 2560 * 128 * 2);
  unsigned short* Vtb = (unsigned short*)alloc(2ull * 16 * 80 * 128 * 32 * 2);
  unsigned short* Obf = (unsigned short*)alloc(2ull * 2560 * 2048 * 2);
  float* rtx = (float*)alloc(4096ull * 64 * 4);  // rope table x: [4096 rows][32][cos,sin]
  float* rty = (float*)alloc(1024ull * 64 * 4);  // rope table y
  if (ws_size < off) return;

  k_f32_to_bf16<<<8192, 256, 0, stream>>>(x, xb, 2097152);
  k_f32_to_bf16<<<2048, 256, 0, stream>>>(y, yb, 524288);
  k_rope_tbl<<<512, 256, 0, stream>>>(tpos, rtx, 4096);
  k_rope_tbl<<<128, 256, 0, stream>>>(ypos, rty, 1024);

  k_transpose<<<dim3(32, 96), 256, 0, stream>>>(Wqkv_x, Wt, 2048, 6144);
  k_gemm<1><<<dim3(32, 48), 256, 0, stream>>>(xb, Wt, bqkv_x, nullptr, Qbf, Kbf, Vtb, qnx, knx,
                                              rtx, 2048, 6144, 2048, 0, 4096, 0, 0);
  k_transpose<<<dim3(32, 96), 256, 0, stream>>>(Wqkv_y, Wt, 2048, 6144);
  k_gemm<1><<<dim3(8, 48), 256, 0, stream>>>(yb, Wt, bqkv_y, nullptr, Qbf, Kbf, Vtb, qny, kny,
                                             rty, 2048, 6144, 512, 2048, 1024, 0, 0);

  k_attn<<<640, 256, 0, stream>>>(Qbf, Kbf, Vtb, Obf);

  k_transpose<<<dim3(32, 32), 256, 0, stream>>>(Wproj_x, Wt, 2048, 2048);
  k_gemm<0><<<dim3(32, 16), 256, 0, stream>>>(Obf, Wt, bproj_x, outp, nullptr, nullptr, nullptr,
                                              nullptr, nullptr, nullptr, 2048, 2048, 0, 0, 2048,
                                              2560, 0);
  k_transpose<<<dim3(32, 32), 256, 0, stream>>>(Wproj_y, Wt, 2048, 2048);
  k_gemm<0><<<dim3(8, 16), 256, 0, stream>>>(Obf, Wt, bproj_y, outp + 8388608ull, nullptr, nullptr,
                                             nullptr, nullptr, nullptr, nullptr, 2048, 2048, 0, 0,
                                             512, 2560, 2048);
}

// Round 11
// 486.331 us; speedup vs baseline: 1.5830x; 1.0837x over previous
//
#include <hip/hip_runtime.h>
#include <stdint.h>

typedef __attribute__((ext_vector_type(8))) short v8s;
typedef __attribute__((ext_vector_type(4))) float v4f;

#define DEV static __device__ __forceinline__

DEV unsigned short f2bf(float f) {
  union { float f; unsigned int u; } v; v.f = f;
  unsigned int u = v.u;
  return (unsigned short)((u + 0x7fffu + ((u >> 16) & 1u)) >> 16);
}

DEV v4f mfma16(v8s a, v8s b, v4f c) {
  return __builtin_amdgcn_mfma_f32_16x16x32_bf16(a, b, c, 0, 0, 0);
}

DEV unsigned int cvtpk(float lo, float hi) {
  unsigned int r;
  asm("v_cvt_pk_bf16_f32 %0, %1, %2" : "=v"(r) : "v"(lo), "v"(hi));
  return r;
}

DEV void async16(const void* g, void* lds) {
  __builtin_amdgcn_global_load_lds((const __attribute__((address_space(1))) unsigned int*)g,
                                   (__attribute__((address_space(3))) unsigned int*)lds,
                                   16, 0, 0);
}

// ---------------- elementwise f32 -> bf16 ----------------
__global__ __launch_bounds__(256) void k_f32_to_bf16(const float* __restrict__ in,
                                                     unsigned short* __restrict__ out, int n4) {
  int i = blockIdx.x * 256 + threadIdx.x;
  if (i < n4) {
    float4 v = reinterpret_cast<const float4*>(in)[i];
    ushort4 o;
    o.x = f2bf(v.x); o.y = f2bf(v.y); o.z = f2bf(v.z); o.w = f2bf(v.w);
    reinterpret_cast<ushort4*>(out)[i] = o;
  }
}

// ---------------- rope table: tbl[row][i] = {cos,sin}(pos[row] * 10000^(-i/32)) ----------------
__global__ __launch_bounds__(256) void k_rope_tbl(const int* __restrict__ pos,
                                                  float* __restrict__ tbl, int nrows) {
  int idx = blockIdx.x * 256 + threadIdx.x;
  if (idx < nrows * 32) {
    int row = idx >> 5, i = idx & 31;
    float ang = (float)pos[row] * expf((float)i * -0.2878231366f);  // ln(1e4)/32
    float sv, cv;
    sincosf(ang, &sv, &cv);
    reinterpret_cast<float2*>(tbl)[(size_t)row * 32 + i] = make_float2(cv, sv);
  }
}

// ---------------- transpose+convert: in [R][C] f32 -> out [C][R] bf16 ----------------
__global__ __launch_bounds__(256) void k_transpose(const float* __restrict__ in,
                                                   unsigned short* __restrict__ out, int R, int C) {
  __shared__ float tile[64][65];
  const int r0 = blockIdx.x * 64, c0 = blockIdx.y * 64;
  const int t = threadIdx.x;
  const int rl = t >> 4, cl = (t & 15) * 4;
#pragma unroll
  for (int p = 0; p < 4; p++) {
    const int r = rl + p * 16;
    float4 v = *reinterpret_cast<const float4*>(&in[(size_t)(r0 + r) * C + c0 + cl]);
    tile[r][cl] = v.x; tile[r][cl + 1] = v.y; tile[r][cl + 2] = v.z; tile[r][cl + 3] = v.w;
  }
  __syncthreads();
  const int cw = t >> 4, rw = (t & 15) * 4;
#pragma unroll
  for (int p = 0; p < 4; p++) {
    const int c = cw + p * 16;
    ushort4 o;
    o.x = f2bf(tile[rw + 0][c]); o.y = f2bf(tile[rw + 1][c]);
    o.z = f2bf(tile[rw + 2][c]); o.w = f2bf(tile[rw + 3][c]);
    *reinterpret_cast<ushort4*>(&out[(size_t)(c0 + c) * R + r0 + rw]) = o;
  }
}

// ---------------- GEMM 128x128 tile, BK=32, 3-deep counted-vmcnt pipeline ----------------
// A/B staged with granule swizzle g^=(row>>1)&3 (pre-swizzled global src, linear LDS dest,
// same XOR on read). MODE 0: Cout = A*Bt^T + bias. MODE 1: fused qkv epilogue.
template <int MODE>
__global__ __launch_bounds__(256) void k_gemm(
    const unsigned short* __restrict__ A, const unsigned short* __restrict__ Bt,
    const float* __restrict__ bias, float* __restrict__ Cout,
    unsigned short* __restrict__ Qb, unsigned short* __restrict__ Kb,
    unsigned short* __restrict__ Vt, const float* __restrict__ qn,
    const float* __restrict__ kn, const float* __restrict__ rtbl, int K, int N, int Nm, int noff,
    int rows_per_b, int b_stride, int row_off) {
  __shared__ __align__(16) char Lds[3 * 16384];  // [buf][A 8KB | B 8KB]
  __shared__ float red[4][64];
  const int m0 = blockIdx.x * 128, n0 = blockIdx.y * 128;
  const int t = threadIdx.x, l = t & 63, w = t >> 6;
  const int lg = l >> 4, li = l & 15;
  const int sr = t >> 2, ss = t & 3;

  auto amap = [&](int m) -> size_t {
    return (size_t)(m / rows_per_b) * b_stride + row_off + (m % rows_per_b);
  };
  const int ssw = (ss ^ ((sr >> 1) & 3)) * 8;  // swizzled source granule (elements)
  const unsigned short* ap0 = A + amap(m0 + sr) * K + ssw;
  const unsigned short* ap1 = A + amap(m0 + sr + 64) * K + ssw;
  const unsigned short* bp0 = Bt + (size_t)(n0 + sr) * K + ssw;
  const unsigned short* bp1 = bp0 + (size_t)64 * K;

  auto stage = [&](char* lb, int st) {
    const int ko = st * 32;
    async16(ap0 + ko, lb + w * 1024);
    async16(ap1 + ko, lb + w * 1024 + 4096);
    async16(bp0 + ko, lb + 8192 + w * 1024);
    async16(bp1 + ko, lb + 8192 + w * 1024 + 4096);
  };

  // hoisted swizzled read byte-offsets
  int aoff[4], boff[4];
#pragma unroll
  for (int mf = 0; mf < 4; mf++) {
    const int row = (w >> 1) * 64 + mf * 16 + li;
    aoff[mf] = row * 64 + ((lg ^ ((row >> 1) & 3)) * 16);
  }
#pragma unroll
  for (int nf = 0; nf < 4; nf++) {
    const int row = (w & 1) * 64 + nf * 16 + li;
    boff[nf] = 8192 + row * 64 + ((lg ^ ((row >> 1) & 3)) * 16);
  }

  v4f acc[4][4] = {};
  const int NK = K >> 5;

  stage(Lds, 0);
  stage(Lds + 16384, 1);
  stage(Lds + 32768, 2);

  int bufc = 0;
  for (int tt = 0; tt < NK; tt++) {
    asm volatile("s_waitcnt vmcnt(8)" ::: "memory");  // stage tt landed (this wave)
    __builtin_amdgcn_sched_barrier(0);
    __builtin_amdgcn_s_barrier();  // all waves' stage tt landed
    __builtin_amdgcn_sched_barrier(0);
    char* Bf = Lds + bufc;
    v8s af[4], bf[4];
#pragma unroll
    for (int mf = 0; mf < 4; mf++) af[mf] = *reinterpret_cast<const v8s*>(Bf + aoff[mf]);
#pragma unroll
    for (int nf = 0; nf < 4; nf++) bf[nf] = *reinterpret_cast<const v8s*>(Bf + boff[nf]);
    __builtin_amdgcn_s_setprio(1);
#pragma unroll
    for (int mf = 0; mf < 4; mf++)
#pragma unroll
      for (int nf = 0; nf < 4; nf++)
        acc[mf][nf] = mfma16(af[mf], bf[nf], acc[mf][nf]);
    __builtin_amdgcn_s_setprio(0);
    __builtin_amdgcn_sched_barrier(0);
    __builtin_amdgcn_s_barrier();  // all waves done reading buf
    __builtin_amdgcn_sched_barrier(0);
    const int st = (tt + 3 < NK) ? tt + 3 : NK - 1;  // tail: reload into dead buffer
    stage(Bf, st);
    bufc += 16384;
    if (bufc == 49152) bufc = 0;
  }
  asm volatile("s_waitcnt vmcnt(0)" ::: "memory");  // drain before epilogue

  const int colh = (w & 1) * 64;
#pragma unroll
  for (int nf = 0; nf < 4; nf++) {
    const float bv = bias[n0 + colh + nf * 16 + li];
#pragma unroll
    for (int mf = 0; mf < 4; mf++)
#pragma unroll
      for (int r = 0; r < 4; r++) acc[mf][nf][r] += bv;
  }

  if (MODE == 0) {
#pragma unroll
    for (int mf = 0; mf < 4; mf++) {
      const int row = m0 + (w >> 1) * 64 + mf * 16 + lg * 4;
#pragma unroll
      for (int nf = 0; nf < 4; nf++) {
        const int col = n0 + colh + nf * 16 + li;
#pragma unroll
        for (int r = 0; r < 4; r++) Cout[(size_t)(row + r) * N + col] = acc[mf][nf][r];
      }
    }
    return;
  }

  // ---- MODE 1 fused qkv epilogue ----
  const int sec = n0 >> 11;  // 0=Q, 1=K, 2=V
  const int h = (n0 >> 7) & 15;
  const int mrow0 = m0 + (w >> 1) * 64;

  if (sec < 2) {
    float ss_[4][4];
#pragma unroll
    for (int mf = 0; mf < 4; mf++)
#pragma unroll
      for (int r = 0; r < 4; r++) {
        float s = 0.f;
#pragma unroll
        for (int nf = 0; nf < 4; nf++) s += acc[mf][nf][r] * acc[mf][nf][r];
#pragma unroll
        for (int off = 1; off < 16; off <<= 1) s += __shfl_xor(s, off, 64);
        ss_[mf][r] = s;
      }
    if (li == 0) {
#pragma unroll
      for (int mf = 0; mf < 4; mf++)
#pragma unroll
        for (int r = 0; r < 4; r++) red[w][mf * 16 + lg * 4 + r] = ss_[mf][r];
    }
    __syncthreads();
    const float* gw = (sec == 0) ? qn : kn;
    unsigned short* Out = (sec == 0) ? Qb : Kb;
    float g[4];
#pragma unroll
    for (int nf = 0; nf < 4; nf++) g[nf] = gw[colh + nf * 16 + li];
#pragma unroll
    for (int mf = 0; mf < 4; mf++) {
#pragma unroll
      for (int r = 0; r < 4; r++) {
        const int m = mrow0 + mf * 16 + lg * 4 + r;
        const float tot = ss_[mf][r] + red[w ^ 1][mf * 16 + lg * 4 + r];
        const float rn = rsqrtf(tot * (1.0f / 128.0f) + 1e-6f);
        float vv[4];
#pragma unroll
        for (int nf = 0; nf < 4; nf++) vv[nf] = acc[mf][nf][r] * rn * g[nf];
        if (colh) {  // upper 64 channels: rope from table. pair (64+i, 96+i), i = nf*16+li
#pragma unroll
          for (int nf = 0; nf < 2; nf++) {
            const float2 cs = reinterpret_cast<const float2*>(rtbl)[(size_t)m * 32 + nf * 16 + li];
            const float v1 = vv[nf], v2 = vv[nf + 2];
            vv[nf] = v1 * cs.x - v2 * cs.y;
            vv[nf + 2] = v2 * cs.x + v1 * cs.y;
          }
        }
        const int b = m / Nm, n = m - b * Nm;
        const size_t base = ((size_t)(b * 16 + h) * 2560 + noff + n) * 128 + colh;
#pragma unroll
        for (int nf = 0; nf < 4; nf++) Out[base + nf * 16 + li] = f2bf(vv[nf]);
      }
    }
  } else {
    // V: write kv-blocked transposed [bh][kb][128 chan][32 keys]
#pragma unroll
    for (int mf = 0; mf < 4; mf++) {
      const int m = mrow0 + mf * 16 + lg * 4;  // 4-row run (keys), multiple of 4
      const int b = m / Nm, n = m - b * Nm;
      const int key = noff + n;
      const size_t base = ((size_t)(b * 16 + h) * 80 + (key >> 5)) * 4096 + (key & 31);
#pragma unroll
      for (int nf = 0; nf < 4; nf++) {
        const int chan = colh + nf * 16 + li;
        ushort4 o;
        o.x = f2bf(acc[mf][nf][0]); o.y = f2bf(acc[mf][nf][1]);
        o.z = f2bf(acc[mf][nf][2]); o.w = f2bf(acc[mf][nf][3]);
        *reinterpret_cast<ushort4*>(&Vt[base + chan * 32]) = o;
      }
    }
  }
}

// ---------------- flash attention (3-deep counted-vmcnt pipeline) ----------------
// grid 640 (XCD-swizzled), block 256. Q,K: [bh][2560][128]; Vt: [bh][80][128][32].
__global__ __launch_bounds__(256) void k_attn(const unsigned short* __restrict__ Qb,
                                              const unsigned short* __restrict__ Kb,
                                              const unsigned short* __restrict__ Vt,
                                              unsigned short* __restrict__ Ob) {
  __shared__ __align__(16) char Ldss[3 * 16384];  // [buf][K 8KB | V 8KB]
  const int NT = 2560;
  const float SC = 0.08838834764831845f;
  const float FM = 12.0f;
  const int i = blockIdx.x;
  const int xcd = i & 7, j = i >> 3;
  const int qt = j % 20;
  const int bh = xcd * 4 + j / 20;
  const int b = bh >> 4, h = bh & 15;
  const int t = threadIdx.x, l = t & 63, w = t >> 6;
  const int lg = l >> 4, li = l & 15;
  const unsigned short* Qbase = Qb + ((size_t)bh * NT + qt * 128) * 128;
  const unsigned short* Kbase = Kb + (size_t)bh * NT * 128;
  const unsigned short* Vbase = Vt + (size_t)bh * 327680;

  v8s qf[2][4];
#pragma unroll
  for (int mg = 0; mg < 2; mg++) {
    const int row = w * 32 + mg * 16 + li;
#pragma unroll
    for (int ds = 0; ds < 4; ds++)
      qf[mg][ds] = *reinterpret_cast<const v8s*>(Qbase + (size_t)row * 128 + (lg + ds * 4) * 8);
  }

  // K staging with in-tile key permutation kappa(rho)=((rho>>2)&3)*8+((rho>>4)&1)*4+(rho&3)
  auto stage = [&](char* lb, int st) {
#pragma unroll
    for (int p = 0; p < 2; p++) {
      const int rho = w * 4 + (l >> 4) + p * 16;
      const int key = ((rho >> 2) & 3) * 8 + ((rho >> 4) & 1) * 4 + (rho & 3);
      const char* g = (const char*)Kbase + ((size_t)(st * 32 + key)) * 256 +
                      (((l & 15) ^ (rho & 7)) * 16);
      async16(g, lb + w * 1024 + p * 4096);
    }
#pragma unroll
    for (int p = 0; p < 2; p++) {
      const int d = w * 32 + p * 16 + (l >> 2);
      const char* g = (const char*)Vbase + (size_t)st * 8192 + d * 64 +
                      ((((l & 3) * 2) ^ (d & 6)) * 8);
      async16(g, lb + 8192 + w * 2048 + p * 1024);
    }
  };

  // hoisted LDS read byte-offsets
  int koff[2][4], voff[8];
#pragma unroll
  for (int kf = 0; kf < 2; kf++)
#pragma unroll
    for (int ds = 0; ds < 4; ds++) {
      const int row = kf * 16 + li;
      koff[kf][ds] = row * 256 + (((lg + ds * 4) ^ (row & 7)) * 16);
    }
#pragma unroll
  for (int df = 0; df < 8; df++) {
    const int d = df * 16 + li;
    voff[df] = 8192 + d * 64 + (((lg * 2) ^ (d & 6)) * 8);
  }

  float ps[2] = {0.f, 0.f};
  v4f O_[2][8] = {};

  stage(Ldss, 0);
  stage(Ldss + 16384, 1);
  stage(Ldss + 32768, 2);

  int bufc = 0;
  for (int tt = 0; tt < 80; tt++) {
    asm volatile("s_waitcnt vmcnt(8)" ::: "memory");  // stage tt landed (this wave)
    __builtin_amdgcn_sched_barrier(0);
    __builtin_amdgcn_s_barrier();  // all waves' stage tt landed
    __builtin_amdgcn_sched_barrier(0);
    char* B = Ldss + bufc;

    // ---- swapped QK^T: s[mg][kf][r] = score(q = mg*16+li, key = lg*8 + kf*4 + r) ----
    v4f s[2][2] = {};
    __builtin_amdgcn_s_setprio(1);
#pragma unroll
    for (int kf = 0; kf < 2; kf++)
#pragma unroll
      for (int ds = 0; ds < 4; ds++) {
        v8s ka = *reinterpret_cast<const v8s*>(B + koff[kf][ds]);
        s[0][kf] = mfma16(ka, qf[0][ds], s[0][kf]);
        s[1][kf] = mfma16(ka, qf[1][ds], s[1][kf]);
      }
    __builtin_amdgcn_s_setprio(0);

    // ---- fixed-max softmax; pack per-lane keys lg*8..lg*8+7 into one v8s A-fragment ----
    v8s pa[2];
#pragma unroll
    for (int mg = 0; mg < 2; mg++) {
      float p[2][4];
#pragma unroll
      for (int kf = 0; kf < 2; kf++)
#pragma unroll
        for (int r = 0; r < 4; r++) {
          p[kf][r] = __expf(fmaf(s[mg][kf][r], SC, -FM));
          ps[mg] += p[kf][r];
        }
      union { v8s v; unsigned int u[4]; } pk;
      pk.u[0] = cvtpk(p[0][0], p[0][1]);
      pk.u[1] = cvtpk(p[0][2], p[0][3]);
      pk.u[2] = cvtpk(p[1][0], p[1][1]);
      pk.u[3] = cvtpk(p[1][2], p[1][3]);
      pa[mg] = pk.v;
    }

    // ---- PV: O[q][d] += P * V via 16x16x32 ----
    __builtin_amdgcn_s_setprio(1);
#pragma unroll
    for (int df = 0; df < 8; df++) {
      v8s vb = *reinterpret_cast<const v8s*>(B + voff[df]);
      O_[0][df] = mfma16(pa[0], vb, O_[0][df]);
      O_[1][df] = mfma16(pa[1], vb, O_[1][df]);
    }
    __builtin_amdgcn_s_setprio(0);

    __builtin_amdgcn_sched_barrier(0);
    __builtin_amdgcn_s_barrier();  // all waves done reading buf tt%3
    __builtin_amdgcn_sched_barrier(0);
    const int st = (tt + 3 < 80) ? tt + 3 : 79;  // tail: reload into dead buffer
    stage(B, st);                                 // (tt+3)%3 == tt%3
    bufc += 16384;
    if (bufc == 49152) bufc = 0;
  }
  asm volatile("s_waitcnt vmcnt(0)" ::: "memory");  // drain before epilogue/exit

  // ---- denominator: sum partials across lg lanes, redistribute to output rows ----
#pragma unroll
  for (int mg = 0; mg < 2; mg++) {
    ps[mg] += __shfl_xor(ps[mg], 16, 64);
    ps[mg] += __shfl_xor(ps[mg], 32, 64);
  }
#pragma unroll
  for (int mg = 0; mg < 2; mg++) {
    float inv[4];
#pragma unroll
    for (int r = 0; r < 4; r++) inv[r] = 1.0f / __shfl(ps[mg], lg * 4 + r, 64);
#pragma unroll
    for (int df = 0; df < 8; df++) {
      const int d = df * 16 + li;
#pragma unroll
      for (int r = 0; r < 4; r++) {
        const int q = qt * 128 + w * 32 + mg * 16 + lg * 4 + r;
        Ob[((size_t)b * NT + q) * 2048 + h * 128 + d] = f2bf(O_[mg][df][r] * inv[r]);
      }
    }
  }
}

// ---------------- host ----------------
extern "C" void kernel_launch(void* const* d_in, const int* in_sizes, int n_in,
                              void* d_out, int out_size, void* d_ws, size_t ws_size,
                              hipStream_t stream) {
  (void)in_sizes; (void)n_in; (void)out_size;
  const float* x = (const float*)d_in[0];
  const float* y = (const float*)d_in[1];
  const int* tpos = (const int*)d_in[2];
  const int* ypos = (const int*)d_in[3];
  const float* Wqkv_x = (const float*)d_in[4];
  const float* bqkv_x = (const float*)d_in[5];
  const float* qnx = (const float*)d_in[6];
  const float* knx = (const float*)d_in[7];
  const float* Wproj_x = (const float*)d_in[8];
  const float* bproj_x = (const float*)d_in[9];
  const float* Wqkv_y = (const float*)d_in[10];
  const float* bqkv_y = (const float*)d_in[11];
  const float* qny = (const float*)d_in[12];
  const float* kny = (const float*)d_in[13];
  const float* Wproj_y = (const float*)d_in[14];
  const float* bproj_y = (const float*)d_in[15];
  float* outp = (float*)d_out;

  char* ws = (char*)d_ws;
  size_t off = 0;
  auto alloc = [&](size_t b) {
    char* p = ws + off;
    off += (b + 255) & ~(size_t)255;
    return p;
  };
  unsigned short* Wt = (unsigned short*)alloc(6144ull * 2048 * 2);
  unsigned short* xb = (unsigned short*)alloc(4096ull * 2048 * 2);
  unsigned short* yb = (unsigned short*)alloc(1024ull * 2048 * 2);
  unsigned short* Qbf = (unsigned short*)alloc(2ull * 16 * 2560 * 128 * 2);
  unsigned short* Kbf = (unsigned short*)alloc(2ull * 16 * 2560 * 128 * 2);
  unsigned short* Vtb = (unsigned short*)alloc(2ull * 16 * 80 * 128 * 32 * 2);
  unsigned short* Obf = (unsigned short*)alloc(2ull * 2560 * 2048 * 2);
  float* rtx = (float*)alloc(4096ull * 64 * 4);  // rope table x: [4096 rows][32][cos,sin]
  float* rty = (float*)alloc(1024ull * 64 * 4);  // rope table y
  if (ws_size < off) return;

  k_f32_to_bf16<<<8192, 256, 0, stream>>>(x, xb, 2097152);
  k_f32_to_bf16<<<2048, 256, 0, stream>>>(y, yb, 524288);
  k_rope_tbl<<<512, 256, 0, stream>>>(tpos, rtx, 4096);
  k_rope_tbl<<<128, 256, 0, stream>>>(ypos, rty, 1024);

  k_transpose<<<dim3(32, 96), 256, 0, stream>>>(Wqkv_x, Wt, 2048, 6144);
  k_gemm<1><<<dim3(32, 48), 256, 0, stream>>>(xb, Wt, bqkv_x, nullptr, Qbf, Kbf, Vtb, qnx, knx,
                                              rtx, 2048, 6144, 2048, 0, 4096, 0, 0);
  k_transpose<<<dim3(32, 96), 256, 0, stream>>>(Wqkv_y, Wt, 2048, 6144);
  k_gemm<1><<<dim3(8, 48), 256, 0, stream>>>(yb, Wt, bqkv_y, nullptr, Qbf, Kbf, Vtb, qny, kny,
                                             rty, 2048, 6144, 512, 2048, 1024, 0, 0);

  k_attn<<<640, 256, 0, stream>>>(Qbf, Kbf, Vtb, Obf);

  k_transpose<<<dim3(32, 32), 256, 0, stream>>>(Wproj_x, Wt, 2048, 2048);
  k_gemm<0><<<dim3(32, 16), 256, 0, stream>>>(Obf, Wt, bproj_x, outp, nullptr, nullptr, nullptr,
                                              nullptr, nullptr, nullptr, 2048, 2048, 0, 0, 2048,
                                              2560, 0);
  k_transpose<<<dim3(32, 32), 256, 0, stream>>>(Wproj_y, Wt, 2048, 2048);
  k_gemm<0><<<dim3(8, 16), 256, 0, stream>>>(Obf, Wt, bproj_y, outp + 8388608ull, nullptr, nullptr,
                                             nullptr, nullptr, nullptr, nullptr, 2048, 2048, 0, 0,
                                             512, 2560, 2048);
}

// Round 12
// 444.179 us; speedup vs baseline: 1.7332x; 1.0949x over previous
//
#include <hip/hip_runtime.h>
#include <stdint.h>

typedef __attribute__((ext_vector_type(8))) short v8s;
typedef __attribute__((ext_vector_type(4))) float v4f;

#define DEV static __device__ __forceinline__

DEV unsigned short f2bf(float f) {
  union { float f; unsigned int u; } v; v.f = f;
  unsigned int u = v.u;
  return (unsigned short)((u + 0x7fffu + ((u >> 16) & 1u)) >> 16);
}

DEV v4f mfma16(v8s a, v8s b, v4f c) {
  return __builtin_amdgcn_mfma_f32_16x16x32_bf16(a, b, c, 0, 0, 0);
}

DEV unsigned int cvtpk(float lo, float hi) {
  unsigned int r;
  asm("v_cvt_pk_bf16_f32 %0, %1, %2" : "=v"(r) : "v"(lo), "v"(hi));
  return r;
}

DEV void async16(const void* g, void* lds) {
  __builtin_amdgcn_global_load_lds((const __attribute__((address_space(1))) unsigned int*)g,
                                   (__attribute__((address_space(3))) unsigned int*)lds,
                                   16, 0, 0);
}

// ---------------- elementwise f32 -> bf16 ----------------
__global__ __launch_bounds__(256) void k_f32_to_bf16(const float* __restrict__ in,
                                                     unsigned short* __restrict__ out, int n4) {
  int i = blockIdx.x * 256 + threadIdx.x;
  if (i < n4) {
    float4 v = reinterpret_cast<const float4*>(in)[i];
    ushort4 o;
    o.x = f2bf(v.x); o.y = f2bf(v.y); o.z = f2bf(v.z); o.w = f2bf(v.w);
    reinterpret_cast<ushort4*>(out)[i] = o;
  }
}

// ---------------- rope table: tbl[row][i] = {cos,sin}(pos[row] * 10000^(-i/32)) ----------------
__global__ __launch_bounds__(256) void k_rope_tbl(const int* __restrict__ pos,
                                                  float* __restrict__ tbl, int nrows) {
  int idx = blockIdx.x * 256 + threadIdx.x;
  if (idx < nrows * 32) {
    int row = idx >> 5, i = idx & 31;
    float ang = (float)pos[row] * expf((float)i * -0.2878231366f);  // ln(1e4)/32
    float sv, cv;
    sincosf(ang, &sv, &cv);
    reinterpret_cast<float2*>(tbl)[(size_t)row * 32 + i] = make_float2(cv, sv);
  }
}

// ---------------- transpose+convert: in [R][C] f32 -> out [C][R] bf16 ----------------
__global__ __launch_bounds__(256) void k_transpose(const float* __restrict__ in,
                                                   unsigned short* __restrict__ out, int R, int C) {
  __shared__ float tile[64][65];
  const int r0 = blockIdx.x * 64, c0 = blockIdx.y * 64;
  const int t = threadIdx.x;
  const int rl = t >> 4, cl = (t & 15) * 4;
#pragma unroll
  for (int p = 0; p < 4; p++) {
    const int r = rl + p * 16;
    float4 v = *reinterpret_cast<const float4*>(&in[(size_t)(r0 + r) * C + c0 + cl]);
    tile[r][cl] = v.x; tile[r][cl + 1] = v.y; tile[r][cl + 2] = v.z; tile[r][cl + 3] = v.w;
  }
  __syncthreads();
  const int cw = t >> 4, rw = (t & 15) * 4;
#pragma unroll
  for (int p = 0; p < 4; p++) {
    const int c = cw + p * 16;
    ushort4 o;
    o.x = f2bf(tile[rw + 0][c]); o.y = f2bf(tile[rw + 1][c]);
    o.z = f2bf(tile[rw + 2][c]); o.w = f2bf(tile[rw + 3][c]);
    *reinterpret_cast<ushort4*>(&out[(size_t)(c0 + c) * R + r0 + rw]) = o;
  }
}

// ---------------- GEMM 128x256 tile, BK=32, 512 threads, 3-deep counted-vmcnt ----------------
// 8 waves in 4(row)x2(col); each wave owns 32 rows x 128 cols (one full head in MODE 1).
// Granule swizzle g^=(row>>1)&3 on both global source and LDS read (linear LDS dest).
// Grid: 1-D, XCD-chunked decode (nwg % 8 == 0). MODE 0: Cout=A*Bt^T+bias. MODE 1: qkv epilogue.
template <int MODE>
__global__ __launch_bounds__(512, 4) void k_gemm(
    const unsigned short* __restrict__ A, const unsigned short* __restrict__ Bt,
    const float* __restrict__ bias, float* __restrict__ Cout,
    unsigned short* __restrict__ Qb, unsigned short* __restrict__ Kb,
    unsigned short* __restrict__ Vt, const float* __restrict__ qn,
    const float* __restrict__ kn, const float* __restrict__ rtbl, int K, int N, int Nm, int noff,
    int rows_per_b, int b_stride, int row_off, int Mb) {
  __shared__ __align__(16) char Lds[3 * 24576];  // [stage][A 8KB | B 16KB]
  const int chunk = gridDim.x >> 3;
  const int o = (blockIdx.x & 7) * chunk + (blockIdx.x >> 3);
  const int m0 = (o % Mb) * 128, n0 = (o / Mb) * 256;
  const int t = threadIdx.x, l = t & 63, w = t >> 6;
  const int lg = l >> 4, li = l & 15;
  const int wr = w >> 1, wc = w & 1;

  auto amap = [&](int m) -> size_t {
    return (size_t)(m / rows_per_b) * b_stride + row_off + (m % rows_per_b);
  };
  const int ar = t >> 2, as = t & 3;
  const int asw = (as ^ ((ar >> 1) & 3)) * 8;  // swizzled source granule (elements)
  const unsigned short* ap = A + amap(m0 + ar) * K + asw;
  const unsigned short* bp0 = Bt + (size_t)(n0 + ar) * K + asw;
  const unsigned short* bp1 = bp0 + (size_t)128 * K;  // (128>>1)&3 == 0: same granule swizzle
  const int t16 = t * 16;

  auto stage = [&](char* lb, int st) {
    const int ko = st * 32;
    async16(ap + ko, lb + t16);
    async16(bp0 + ko, lb + 8192 + t16);
    async16(bp1 + ko, lb + 16384 + t16);
  };

  // hoisted swizzled read byte-offsets
  int aoff[2], boff[8];
#pragma unroll
  for (int mf = 0; mf < 2; mf++) {
    const int row = wr * 32 + mf * 16 + li;
    aoff[mf] = row * 64 + ((lg ^ ((row >> 1) & 3)) * 16);
  }
#pragma unroll
  for (int nf = 0; nf < 8; nf++) {
    const int row = wc * 128 + nf * 16 + li;
    boff[nf] = 8192 + row * 64 + ((lg ^ ((row >> 1) & 3)) * 16);
  }

  v4f acc[2][8] = {};
  const int NK = K >> 5;

  stage(Lds, 0);
  stage(Lds + 24576, 1);
  stage(Lds + 49152, 2);

  int bufc = 0;
  for (int tt = 0; tt < NK; tt++) {
    asm volatile("s_waitcnt vmcnt(6)" ::: "memory");  // stage tt landed (this wave)
    __builtin_amdgcn_sched_barrier(0);
    __builtin_amdgcn_s_barrier();  // all waves' stage tt landed
    __builtin_amdgcn_sched_barrier(0);
    char* Bf = Lds + bufc;
    v8s af0 = *reinterpret_cast<const v8s*>(Bf + aoff[0]);
    v8s af1 = *reinterpret_cast<const v8s*>(Bf + aoff[1]);
    __builtin_amdgcn_s_setprio(1);
#pragma unroll
    for (int nf = 0; nf < 8; nf++) {
      v8s bfv = *reinterpret_cast<const v8s*>(Bf + boff[nf]);
      acc[0][nf] = mfma16(af0, bfv, acc[0][nf]);
      acc[1][nf] = mfma16(af1, bfv, acc[1][nf]);
    }
    __builtin_amdgcn_s_setprio(0);
    __builtin_amdgcn_sched_barrier(0);
    __builtin_amdgcn_s_barrier();  // all waves done reading buf
    __builtin_amdgcn_sched_barrier(0);
    stage(Bf, (tt + 3 < NK) ? tt + 3 : NK - 1);  // tail: reload into dead buffer
    bufc += 24576;
    if (bufc == 73728) bufc = 0;
  }
  asm volatile("s_waitcnt vmcnt(0)" ::: "memory");  // drain before epilogue

#pragma unroll
  for (int nf = 0; nf < 8; nf++) {
    const float bv = bias[n0 + wc * 128 + nf * 16 + li];
#pragma unroll
    for (int mf = 0; mf < 2; mf++)
#pragma unroll
      for (int r = 0; r < 4; r++) acc[mf][nf][r] += bv;
  }

  if (MODE == 0) {
#pragma unroll
    for (int mf = 0; mf < 2; mf++) {
      const int row = m0 + wr * 32 + mf * 16 + lg * 4;
#pragma unroll
      for (int nf = 0; nf < 8; nf++) {
        const int col = n0 + wc * 128 + nf * 16 + li;
#pragma unroll
        for (int r = 0; r < 4; r++) Cout[(size_t)(row + r) * N + col] = acc[mf][nf][r];
      }
    }
    return;
  }

  // ---- MODE 1 fused qkv epilogue; this wave owns one full head (128 channels) ----
  const int sec = n0 >> 11;  // 0=Q, 1=K, 2=V
  const int hh = ((n0 + wc * 128) >> 7) & 15;
  const int mrow0 = m0 + wr * 32;

  if (sec < 2) {
    const float* gw = (sec == 0) ? qn : kn;
    unsigned short* Out = (sec == 0) ? Qb : Kb;
    float g[8];
#pragma unroll
    for (int nf = 0; nf < 8; nf++) g[nf] = gw[nf * 16 + li];
#pragma unroll
    for (int mf = 0; mf < 2; mf++) {
#pragma unroll
      for (int r = 0; r < 4; r++) {
        float s = 0.f;
#pragma unroll
        for (int nf = 0; nf < 8; nf++) s += acc[mf][nf][r] * acc[mf][nf][r];
#pragma unroll
        for (int off = 1; off < 16; off <<= 1) s += __shfl_xor(s, off, 64);
        const int m = mrow0 + mf * 16 + lg * 4 + r;
        const float rn = rsqrtf(s * (1.0f / 128.0f) + 1e-6f);
        float vv[8];
#pragma unroll
        for (int nf = 0; nf < 8; nf++) vv[nf] = acc[mf][nf][r] * rn * g[nf];
        // rope: channels 64..127; pair (64+i, 96+i), i = (nf-4)*16+li for nf in {4,5}
#pragma unroll
        for (int nf = 4; nf < 6; nf++) {
          const float2 cs =
              reinterpret_cast<const float2*>(rtbl)[(size_t)m * 32 + (nf - 4) * 16 + li];
          const float v1 = vv[nf], v2 = vv[nf + 2];
          vv[nf] = v1 * cs.x - v2 * cs.y;
          vv[nf + 2] = v2 * cs.x + v1 * cs.y;
        }
        const int b = m / Nm, n = m - b * Nm;
        const size_t base = ((size_t)(b * 16 + hh) * 2560 + noff + n) * 128;
#pragma unroll
        for (int nf = 0; nf < 8; nf++) Out[base + nf * 16 + li] = f2bf(vv[nf]);
      }
    }
  } else {
    // V: write kv-blocked transposed [bh][kb][128 chan][32 keys]
#pragma unroll
    for (int mf = 0; mf < 2; mf++) {
      const int m = mrow0 + mf * 16 + lg * 4;  // 4-key run, multiple of 4
      const int b = m / Nm, n = m - b * Nm;
      const int key = noff + n;
      const size_t base = ((size_t)(b * 16 + hh) * 80 + (key >> 5)) * 4096 + (key & 31);
#pragma unroll
      for (int nf = 0; nf < 8; nf++) {
        const int chan = nf * 16 + li;
        ushort4 ov;
        ov.x = f2bf(acc[mf][nf][0]); ov.y = f2bf(acc[mf][nf][1]);
        ov.z = f2bf(acc[mf][nf][2]); ov.w = f2bf(acc[mf][nf][3]);
        *reinterpret_cast<ushort4*>(&Vt[base + chan * 32]) = ov;
      }
    }
  }
}

// ---------------- flash attention (3-deep counted-vmcnt pipeline) ----------------
// grid 640 (XCD-swizzled), block 256. Q,K: [bh][2560][128]; Vt: [bh][80][128][32].
__global__ __launch_bounds__(256) void k_attn(const unsigned short* __restrict__ Qb,
                                              const unsigned short* __restrict__ Kb,
                                              const unsigned short* __restrict__ Vt,
                                              unsigned short* __restrict__ Ob) {
  __shared__ __align__(16) char Ldss[3 * 16384];  // [buf][K 8KB | V 8KB]
  const int NT = 2560;
  const float SC = 0.08838834764831845f;
  const float FM = 12.0f;
  const int i = blockIdx.x;
  const int xcd = i & 7, j = i >> 3;
  const int qt = j % 20;
  const int bh = xcd * 4 + j / 20;
  const int b = bh >> 4, h = bh & 15;
  const int t = threadIdx.x, l = t & 63, w = t >> 6;
  const int lg = l >> 4, li = l & 15;
  const unsigned short* Qbase = Qb + ((size_t)bh * NT + qt * 128) * 128;
  const unsigned short* Kbase = Kb + (size_t)bh * NT * 128;
  const unsigned short* Vbase = Vt + (size_t)bh * 327680;

  v8s qf[2][4];
#pragma unroll
  for (int mg = 0; mg < 2; mg++) {
    const int row = w * 32 + mg * 16 + li;
#pragma unroll
    for (int ds = 0; ds < 4; ds++)
      qf[mg][ds] = *reinterpret_cast<const v8s*>(Qbase + (size_t)row * 128 + (lg + ds * 4) * 8);
  }

  // K staging with in-tile key permutation kappa(rho)=((rho>>2)&3)*8+((rho>>4)&1)*4+(rho&3)
  auto stage = [&](char* lb, int st) {
#pragma unroll
    for (int p = 0; p < 2; p++) {
      const int rho = w * 4 + (l >> 4) + p * 16;
      const int key = ((rho >> 2) & 3) * 8 + ((rho >> 4) & 1) * 4 + (rho & 3);
      const char* g = (const char*)Kbase + ((size_t)(st * 32 + key)) * 256 +
                      (((l & 15) ^ (rho & 7)) * 16);
      async16(g, lb + w * 1024 + p * 4096);
    }
#pragma unroll
    for (int p = 0; p < 2; p++) {
      const int d = w * 32 + p * 16 + (l >> 2);
      const char* g = (const char*)Vbase + (size_t)st * 8192 + d * 64 +
                      ((((l & 3) * 2) ^ (d & 6)) * 8);
      async16(g, lb + 8192 + w * 2048 + p * 1024);
    }
  };

  // hoisted LDS read byte-offsets
  int koff[2][4], voff[8];
#pragma unroll
  for (int kf = 0; kf < 2; kf++)
#pragma unroll
    for (int ds = 0; ds < 4; ds++) {
      const int row = kf * 16 + li;
      koff[kf][ds] = row * 256 + (((lg + ds * 4) ^ (row & 7)) * 16);
    }
#pragma unroll
  for (int df = 0; df < 8; df++) {
    const int d = df * 16 + li;
    voff[df] = 8192 + d * 64 + (((lg * 2) ^ (d & 6)) * 8);
  }

  float ps[2] = {0.f, 0.f};
  v4f O_[2][8] = {};

  stage(Ldss, 0);
  stage(Ldss + 16384, 1);
  stage(Ldss + 32768, 2);

  int bufc = 0;
  for (int tt = 0; tt < 80; tt++) {
    asm volatile("s_waitcnt vmcnt(8)" ::: "memory");  // stage tt landed (this wave)
    __builtin_amdgcn_sched_barrier(0);
    __builtin_amdgcn_s_barrier();  // all waves' stage tt landed
    __builtin_amdgcn_sched_barrier(0);
    char* B = Ldss + bufc;

    // ---- swapped QK^T: s[mg][kf][r] = score(q = mg*16+li, key = lg*8 + kf*4 + r) ----
    v4f s[2][2] = {};
    __builtin_amdgcn_s_setprio(1);
#pragma unroll
    for (int kf = 0; kf < 2; kf++)
#pragma unroll
      for (int ds = 0; ds < 4; ds++) {
        v8s ka = *reinterpret_cast<const v8s*>(B + koff[kf][ds]);
        s[0][kf] = mfma16(ka, qf[0][ds], s[0][kf]);
        s[1][kf] = mfma16(ka, qf[1][ds], s[1][kf]);
      }
    __builtin_amdgcn_s_setprio(0);

    // ---- fixed-max softmax; pack per-lane keys lg*8..lg*8+7 into one v8s A-fragment ----
    v8s pa[2];
#pragma unroll
    for (int mg = 0; mg < 2; mg++) {
      float p[2][4];
#pragma unroll
      for (int kf = 0; kf < 2; kf++)
#pragma unroll
        for (int r = 0; r < 4; r++) {
          p[kf][r] = __expf(fmaf(s[mg][kf][r], SC, -FM));
          ps[mg] += p[kf][r];
        }
      union { v8s v; unsigned int u[4]; } pk;
      pk.u[0] = cvtpk(p[0][0], p[0][1]);
      pk.u[1] = cvtpk(p[0][2], p[0][3]);
      pk.u[2] = cvtpk(p[1][0], p[1][1]);
      pk.u[3] = cvtpk(p[1][2], p[1][3]);
      pa[mg] = pk.v;
    }

    // ---- PV: O[q][d] += P * V via 16x16x32 ----
    __builtin_amdgcn_s_setprio(1);
#pragma unroll
    for (int df = 0; df < 8; df++) {
      v8s vb = *reinterpret_cast<const v8s*>(B + voff[df]);
      O_[0][df] = mfma16(pa[0], vb, O_[0][df]);
      O_[1][df] = mfma16(pa[1], vb, O_[1][df]);
    }
    __builtin_amdgcn_s_setprio(0);

    __builtin_amdgcn_sched_barrier(0);
    __builtin_amdgcn_s_barrier();  // all waves done reading buf tt%3
    __builtin_amdgcn_sched_barrier(0);
    const int st = (tt + 3 < 80) ? tt + 3 : 79;  // tail: reload into dead buffer
    stage(B, st);                                 // (tt+3)%3 == tt%3
    bufc += 16384;
    if (bufc == 49152) bufc = 0;
  }
  asm volatile("s_waitcnt vmcnt(0)" ::: "memory");  // drain before epilogue/exit

  // ---- denominator: sum partials across lg lanes, redistribute to output rows ----
#pragma unroll
  for (int mg = 0; mg < 2; mg++) {
    ps[mg] += __shfl_xor(ps[mg], 16, 64);
    ps[mg] += __shfl_xor(ps[mg], 32, 64);
  }
#pragma unroll
  for (int mg = 0; mg < 2; mg++) {
    float inv[4];
#pragma unroll
    for (int r = 0; r < 4; r++) inv[r] = 1.0f / __shfl(ps[mg], lg * 4 + r, 64);
#pragma unroll
    for (int df = 0; df < 8; df++) {
      const int d = df * 16 + li;
#pragma unroll
      for (int r = 0; r < 4; r++) {
        const int q = qt * 128 + w * 32 + mg * 16 + lg * 4 + r;
        Ob[((size_t)b * NT + q) * 2048 + h * 128 + d] = f2bf(O_[mg][df][r] * inv[r]);
      }
    }
  }
}

// ---------------- host ----------------
extern "C" void kernel_launch(void* const* d_in, const int* in_sizes, int n_in,
                              void* d_out, int out_size, void* d_ws, size_t ws_size,
                              hipStream_t stream) {
  (void)in_sizes; (void)n_in; (void)out_size;
  const float* x = (const float*)d_in[0];
  const float* y = (const float*)d_in[1];
  const int* tpos = (const int*)d_in[2];
  const int* ypos = (const int*)d_in[3];
  const float* Wqkv_x = (const float*)d_in[4];
  const float* bqkv_x = (const float*)d_in[5];
  const float* qnx = (const float*)d_in[6];
  const float* knx = (const float*)d_in[7];
  const float* Wproj_x = (const float*)d_in[8];
  const float* bproj_x = (const float*)d_in[9];
  const float* Wqkv_y = (const float*)d_in[10];
  const float* bqkv_y = (const float*)d_in[11];
  const float* qny = (const float*)d_in[12];
  const float* kny = (const float*)d_in[13];
  const float* Wproj_y = (const float*)d_in[14];
  const float* bproj_y = (const float*)d_in[15];
  float* outp = (float*)d_out;

  char* ws = (char*)d_ws;
  size_t off = 0;
  auto alloc = [&](size_t b) {
    char* p = ws + off;
    off += (b + 255) & ~(size_t)255;
    return p;
  };
  unsigned short* Wt = (unsigned short*)alloc(6144ull * 2048 * 2);
  unsigned short* xb = (unsigned short*)alloc(4096ull * 2048 * 2);
  unsigned short* yb = (unsigned short*)alloc(1024ull * 2048 * 2);
  unsigned short* Qbf = (unsigned short*)alloc(2ull * 16 * 2560 * 128 * 2);
  unsigned short* Kbf = (unsigned short*)alloc(2ull * 16 * 2560 * 128 * 2);
  unsigned short* Vtb = (unsigned short*)alloc(2ull * 16 * 80 * 128 * 32 * 2);
  unsigned short* Obf = (unsigned short*)alloc(2ull * 2560 * 2048 * 2);
  float* rtx = (float*)alloc(4096ull * 64 * 4);  // rope table x: [4096 rows][32][cos,sin]
  float* rty = (float*)alloc(1024ull * 64 * 4);  // rope table y
  if (ws_size < off) return;

  k_f32_to_bf16<<<8192, 256, 0, stream>>>(x, xb, 2097152);
  k_f32_to_bf16<<<2048, 256, 0, stream>>>(y, yb, 524288);
  k_rope_tbl<<<512, 256, 0, stream>>>(tpos, rtx, 4096);
  k_rope_tbl<<<128, 256, 0, stream>>>(ypos, rty, 1024);

  k_transpose<<<dim3(32, 96), 256, 0, stream>>>(Wqkv_x, Wt, 2048, 6144);
  k_gemm<1><<<768, 512, 0, stream>>>(xb, Wt, bqkv_x, nullptr, Qbf, Kbf, Vtb, qnx, knx, rtx, 2048,
                                     6144, 2048, 0, 4096, 0, 0, 32);
  k_transpose<<<dim3(32, 96), 256, 0, stream>>>(Wqkv_y, Wt, 2048, 6144);
  k_gemm<1><<<192, 512, 0, stream>>>(yb, Wt, bqkv_y, nullptr, Qbf, Kbf, Vtb, qny, kny, rty, 2048,
                                     6144, 512, 2048, 1024, 0, 0, 8);

  k_attn<<<640, 256, 0, stream>>>(Qbf, Kbf, Vtb, Obf);

  k_transpose<<<dim3(32, 32), 256, 0, stream>>>(Wproj_x, Wt, 2048, 2048);
  k_gemm<0><<<256, 512, 0, stream>>>(Obf, Wt, bproj_x, outp, nullptr, nullptr, nullptr, nullptr,
                                     nullptr, nullptr, 2048, 2048, 0, 0, 2048, 2560, 0, 32);
  k_transpose<<<dim3(32, 32), 256, 0, stream>>>(Wproj_y, Wt, 2048, 2048);
  k_gemm<0><<<64, 512, 0, stream>>>(Obf, Wt, bproj_y, outp + 8388608ull, nullptr, nullptr, nullptr,
                                    nullptr, nullptr, nullptr, 2048, 2048, 0, 0, 512, 2560, 2048,
                                    8);
}